// Round 1
// 901.941 us; speedup vs baseline: 1.2226x; 1.2226x over previous
//
#include <hip/hip_runtime.h>
#include <math.h>

#define BB 256
#define DD 256
#define VV 2000
#define VT 10000
#define OPTN 16
#define SEQN 10
#define SRCN 40
#define D3 768
#define D2 512

#define LOG_TINY (-29.9336062f)

// output offsets (floats)
#define OFF_OPTS  (2*BB + BB*OPTN*4*SEQN)          // 164352
#define OFF_TOPO  (OFF_OPTS + BB*OPTN)             // 168448
#define OFF_EXACT (OFF_TOPO + 4*BB*SEQN)           // 178688

// tok bitmask: 2000 rows x 320 dwords (10240 bits >= 10000)
#define TOKB_STRIDE 320

typedef __bf16 bf16x8 __attribute__((ext_vector_type(8)));
typedef float  f32x4  __attribute__((ext_vector_type(4)));

__device__ __forceinline__ float sigm(float x){ return 1.0f/(1.0f+expf(-x)); }
__device__ __forceinline__ unsigned short f2bf(float x){
  union { float f; unsigned int u; } v; v.f = x;
  unsigned int r = (v.u + 0x7FFF + ((v.u >> 16) & 1)) >> 16;
  return (unsigned short)r;
}

// gh = tree_state @ Wh + bh  (constant across steps: gru uses outer tree_state)
__global__ void k_gh(const float* __restrict__ ts0, const float* __restrict__ Wh,
                     const float* __restrict__ bh, float* __restrict__ gh){
  int b = blockIdx.x;
  int j = blockIdx.y*256 + threadIdx.x;
  __shared__ float hsh[DD];
  hsh[threadIdx.x] = ts0[b*DD + threadIdx.x];
  __syncthreads();
  float a0 = bh[j], a1 = 0.f, a2 = 0.f, a3 = 0.f;
  #pragma unroll 4
  for(int k=0;k<DD;k+=4){
    a0 = fmaf(hsh[k+0], Wh[(k+0)*D3 + j], a0);
    a1 = fmaf(hsh[k+1], Wh[(k+1)*D3 + j], a1);
    a2 = fmaf(hsh[k+2], Wh[(k+2)*D3 + j], a2);
    a3 = fmaf(hsh[k+3], Wh[(k+3)*D3 + j], a3);
  }
  gh[b*D3 + j] = (a0+a1)+(a2+a3);
}

// EW = emb @ Wx  (2000 x 768, K=256) fp32 64x64 tiler
__global__ void k_ew(const float* __restrict__ emb, const float* __restrict__ Wx,
                     float* __restrict__ EW){
  __shared__ float As[16][64];
  __shared__ float Bs[16][64];
  int tid = threadIdx.x;
  int tx = tid & 15, ty = tid >> 4;
  int m0 = blockIdx.y*64, n0 = blockIdx.x*64;
  float acc[4][4];
  #pragma unroll
  for(int i=0;i<4;i++){ acc[i][0]=0.f; acc[i][1]=0.f; acc[i][2]=0.f; acc[i][3]=0.f; }
  for(int k0=0;k0<DD;k0+=16){
    {
      int row = tid >> 2, kk = (tid & 3)*4;
      int m = m0 + row;
      float4 av = {0,0,0,0};
      if(m < VV) av = *(const float4*)&emb[m*DD + k0 + kk];
      As[kk+0][row]=av.x; As[kk+1][row]=av.y; As[kk+2][row]=av.z; As[kk+3][row]=av.w;
    }
    {
      int r = tid >> 4, c2 = (tid & 15)*4;
      float4 bv = *(const float4*)&Wx[(k0+r)*D3 + n0 + c2];
      *(float4*)&Bs[r][c2] = bv;
    }
    __syncthreads();
    #pragma unroll
    for(int k=0;k<16;k++){
      float4 a4 = *(const float4*)&As[k][ty*4];
      float4 b4 = *(const float4*)&Bs[k][tx*4];
      float av[4] = {a4.x,a4.y,a4.z,a4.w};
      float bw[4] = {b4.x,b4.y,b4.z,b4.w};
      #pragma unroll
      for(int i=0;i<4;i++)
        #pragma unroll
        for(int j=0;j<4;j++) acc[i][j] = fmaf(av[i], bw[j], acc[i][j]);
    }
    __syncthreads();
  }
  #pragma unroll
  for(int i=0;i<4;i++){
    int m = m0 + ty*4 + i;
    if(m < VV){
      #pragma unroll
      for(int j=0;j<4;j++) EW[m*D3 + n0 + tx*4 + j] = acc[i][j];
    }
  }
}

// Wtok [512][10000] fp32 -> WtokB [10000][512] bf16 (transpose + convert)
__global__ void k_wtokT(const float* __restrict__ Wtok, unsigned short* __restrict__ WtokB){
  __shared__ float tile[32][65];
  int tid = threadIdx.x;
  int n0 = blockIdx.x*64, k0 = blockIdx.y*32;
  #pragma unroll
  for(int p=0;p<8;p++){
    int idx = tid + p*256;
    int kk = idx >> 6, nn = idx & 63;
    int n = n0 + nn;
    tile[kk][nn] = (n < VT) ? Wtok[(size_t)(k0+kk)*VT + n] : 0.f;
  }
  __syncthreads();
  #pragma unroll
  for(int p=0;p<4;p++){
    int idx = tid + p*256;
    int nn = idx >> 4, kk = (idx & 15)*2;
    int n = n0 + nn;
    if(n < VT){
      ushort2 v;
      v.x = f2bf(tile[kk][nn]);
      v.y = f2bf(tile[kk+1][nn]);
      *(ushort2*)&WtokB[(size_t)n*D2 + k0 + kk] = v;
    }
  }
}

// tok_table (binary 0/1) -> bitmask, 1 bit per entry.
// log(tt + 1e-13) == (tt ? 0 : LOG_TINY) EXACTLY in fp32, so the 80MB fp32
// table compresses to a 2.5MB L2-resident bitmask.
__global__ __launch_bounds__(256) void k_tokbits(const float* __restrict__ tok_table,
                                                 unsigned int* __restrict__ bits){
  int v = blockIdx.y;
  int n = blockIdx.x*256 + threadIdx.x;
  float val = (n < VT) ? tok_table[(size_t)v*VT + n] : 0.f;
  unsigned long long m = __ballot(val > 0.5f);
  if((threadIdx.x & 63) == 0){
    int w = (blockIdx.x*256 + (threadIdx.x & ~63)) >> 5;
    bits[v*TOKB_STRIDE + w]     = (unsigned int)(m & 0xFFFFFFFFull);
    bits[v*TOKB_STRIDE + w + 1] = (unsigned int)(m >> 32);
  }
}

// fused per-step: argmax(cl[t-1]) -> sym; gates from EW gather; gru; attention;
// soa=tanh([ctx,h]@Wc+bc); ts update
__global__ void k_step(const float* __restrict__ cl_prev, const int* __restrict__ lhs,
                       const float* __restrict__ EW, const float* __restrict__ gh,
                       const float* __restrict__ bx, const float* __restrict__ ts0,
                       const float* __restrict__ mem, const float* __restrict__ Wc,
                       const float* __restrict__ bc, float* __restrict__ soa,
                       float* __restrict__ ts){
  int b = blockIdx.x, tid = threadIdx.x;
  __shared__ float hs[DD], cs[DD], sc[SRCN];
  __shared__ float smx[256]; __shared__ int smi[256];
  __shared__ int sym_sh;
  int sym;
  if(cl_prev){
    const float* row = cl_prev + (size_t)b*VV;
    float mx = -1e30f; int mi = 0;
    for(int v=tid; v<VV; v+=256){
      float val = row[v];
      if(val > mx){ mx = val; mi = v; }
    }
    smx[tid]=mx; smi[tid]=mi; __syncthreads();
    for(int s=128; s; s>>=1){
      if(tid < s){
        if(smx[tid+s] > smx[tid] || (smx[tid+s]==smx[tid] && smi[tid+s] < smi[tid])){
          smx[tid]=smx[tid+s]; smi[tid]=smi[tid+s];
        }
      }
      __syncthreads();
    }
    if(tid==0) sym_sh = smi[0];
    __syncthreads();
    sym = sym_sh;
  } else {
    sym = lhs[b];
  }
  const float* ew = EW + sym*D3;
  const float* ghb = gh + b*D3;
  float r = sigm(ew[tid]     + bx[tid]     + ghb[tid]);
  float z = sigm(ew[256+tid] + bx[256+tid] + ghb[256+tid]);
  float n = tanhf(ew[512+tid] + bx[512+tid] + r*ghb[512+tid]);
  float h = (1.0f - z)*n + z*ts0[b*DD + tid];
  hs[tid] = h;
  __syncthreads();
  int lane = tid & 63, wv = tid >> 6;
  for(int s = wv; s < SRCN; s += 4){
    float p = 0.f;
    const float* mrow = mem + (size_t)(b*SRCN + s)*DD;
    #pragma unroll 4
    for(int d = lane; d < DD; d += 64) p = fmaf(hs[d], mrow[d], p);
    for(int off=32; off; off>>=1) p += __shfl_down(p, off, 64);
    if(lane==0) sc[s] = p;
  }
  __syncthreads();
  // wave-parallel softmax over the 40 scores (first wave only)
  if(tid < 64){
    float v = (tid < SRCN) ? sc[tid] : -1e30f;
    float mx = v;
    for(int off=32; off; off>>=1) mx = fmaxf(mx, __shfl_xor(mx, off, 64));
    float e = (tid < SRCN) ? expf(v - mx) : 0.f;
    float sum = e;
    for(int off=32; off; off>>=1) sum += __shfl_xor(sum, off, 64);
    if(tid < SRCN) sc[tid] = e / sum;
  }
  __syncthreads();
  float c = 0.f;
  #pragma unroll 8
  for(int s=0;s<SRCN;s++) c = fmaf(sc[s], mem[(size_t)(b*SRCN+s)*DD + tid], c);
  cs[tid] = c;
  __syncthreads();
  // [ctx|h] @ Wc — 4 independent accumulators (1 wave/SIMD here: the serial
  // 512-FMA chain is latency-exposed otherwise)
  float a0 = bc[tid], a1 = 0.f, a2 = 0.f, a3 = 0.f;
  #pragma unroll 4
  for(int k=0;k<DD;k+=4){
    a0 = fmaf(cs[k+0], Wc[(k+0)*DD + tid], a0);
    a1 = fmaf(cs[k+1], Wc[(k+1)*DD + tid], a1);
    a2 = fmaf(cs[k+2], Wc[(k+2)*DD + tid], a2);
    a3 = fmaf(cs[k+3], Wc[(k+3)*DD + tid], a3);
  }
  #pragma unroll 4
  for(int k=0;k<DD;k+=4){
    a0 = fmaf(hs[k+0], Wc[(k+0+DD)*DD + tid], a0);
    a1 = fmaf(hs[k+1], Wc[(k+1+DD)*DD + tid], a1);
    a2 = fmaf(hs[k+2], Wc[(k+2+DD)*DD + tid], a2);
    a3 = fmaf(hs[k+3], Wc[(k+3+DD)*DD + tid], a3);
  }
  float sv = tanhf((a0+a1)+(a2+a3));
  soa[b*DD + tid] = sv;
  ts[b*DD + tid] = tanhf(ts[b*DD + tid] + sv);
}

// clogits[t][b][v] = soa[b]@Wsym[:,v] + bsym[v] + (allowed? 0 : LOG_TINY)
__global__ void k_clogits(const float* __restrict__ A, const float* __restrict__ Wsym,
                          const float* __restrict__ bsym, const int* __restrict__ gg,
                          int t, float* __restrict__ cl){
  __shared__ float As[16][64];
  __shared__ float Bs[16][64];
  __shared__ int sel[64][OPTN];
  int tid = threadIdx.x;
  int tx = tid & 15, ty = tid >> 4;
  int m0 = blockIdx.y*64, n0 = blockIdx.x*64;
  for(int idx = tid; idx < 64*OPTN; idx += 256){
    int i = idx >> 4, o = idx & 15;
    int bb = m0 + i;
    int base = ((bb*OPTN + o)*4)*SEQN + t;
    int mk = gg[base + 3*SEQN];
    sel[i][o] = mk ? gg[base] : -1;
  }
  float acc[4][4];
  #pragma unroll
  for(int i=0;i<4;i++){ acc[i][0]=0.f; acc[i][1]=0.f; acc[i][2]=0.f; acc[i][3]=0.f; }
  for(int k0=0;k0<DD;k0+=16){
    {
      int row = tid >> 2, kk = (tid & 3)*4;
      float4 av = *(const float4*)&A[(m0+row)*DD + k0 + kk];
      As[kk+0][row]=av.x; As[kk+1][row]=av.y; As[kk+2][row]=av.z; As[kk+3][row]=av.w;
    }
    {
      int r = tid >> 4, c2 = (tid & 15)*4;
      int n = n0 + c2;
      float4 bv;
      if(n + 3 < VV){ bv = *(const float4*)&Wsym[(k0+r)*VV + n]; }
      else {
        bv.x = (n+0<VV)? Wsym[(k0+r)*VV + n+0] : 0.f;
        bv.y = (n+1<VV)? Wsym[(k0+r)*VV + n+1] : 0.f;
        bv.z = (n+2<VV)? Wsym[(k0+r)*VV + n+2] : 0.f;
        bv.w = (n+3<VV)? Wsym[(k0+r)*VV + n+3] : 0.f;
      }
      *(float4*)&Bs[r][c2] = bv;
    }
    __syncthreads();
    #pragma unroll
    for(int k=0;k<16;k++){
      float4 a4 = *(const float4*)&As[k][ty*4];
      float4 b4 = *(const float4*)&Bs[k][tx*4];
      float av[4] = {a4.x,a4.y,a4.z,a4.w};
      float bw[4] = {b4.x,b4.y,b4.z,b4.w};
      #pragma unroll
      for(int i=0;i<4;i++)
        #pragma unroll
        for(int j=0;j<4;j++) acc[i][j] = fmaf(av[i], bw[j], acc[i][j]);
    }
    __syncthreads();
  }
  #pragma unroll
  for(int i=0;i<4;i++){
    int m = m0 + ty*4 + i;
    #pragma unroll
    for(int j=0;j<4;j++){
      int n = n0 + tx*4 + j;
      if(n < VV){
        bool allowed = false;
        #pragma unroll
        for(int o=0;o<OPTN;o++) allowed |= (sel[ty*4+i][o] == n);
        cl[((size_t)t*BB + m)*VV + n] = acc[i][j] + bsym[n] + (allowed? 0.f : LOG_TINY);
      }
    }
  }
}

// per-b: lse for all t; opts_logp; best; topo outputs; sym_i; build bf16 A rows
__global__ void k_opts(const float* __restrict__ cl, const int* __restrict__ gg,
                       const float* __restrict__ emb, const float* __restrict__ ts,
                       float* __restrict__ out, int* __restrict__ sym_i,
                       unsigned short* __restrict__ A){
  int b = blockIdx.x, tid = threadIdx.x;
  __shared__ float red[256];
  __shared__ float lse_sh[SEQN];
  __shared__ float sacc[OPTN];
  __shared__ int ssym[SEQN];
  __shared__ int sbest;
  for(int t=0;t<SEQN;t++){
    const float* row = cl + ((size_t)t*BB + b)*VV;
    float mx = -1e30f;
    for(int v=tid; v<VV; v+=256) mx = fmaxf(mx, row[v]);
    red[tid]=mx; __syncthreads();
    for(int s=128;s;s>>=1){ if(tid<s) red[tid]=fmaxf(red[tid],red[tid+s]); __syncthreads(); }
    float gmx = red[0]; __syncthreads();
    float sum = 0.f;
    for(int v=tid; v<VV; v+=256) sum += expf(row[v]-gmx);
    red[tid]=sum; __syncthreads();
    for(int s=128;s;s>>=1){ if(tid<s) red[tid]+=red[tid+s]; __syncthreads(); }
    if(tid==0) lse_sh[t] = gmx + logf(red[0]);
    __syncthreads();
  }
  if(tid < OPTN){
    int o = tid;
    float acc = 0.f;
    for(int t=0;t<SEQN;t++){
      int base = ((b*OPTN + o)*4)*SEQN + t;
      int mk = gg[base + 3*SEQN];
      if(mk){
        int v = gg[base];
        float p = expf(cl[((size_t)t*BB + b)*VV + v] - lse_sh[t]);
        acc += logf(p + 1e-13f);
      }
    }
    sacc[o] = acc;
    out[OFF_OPTS + b*OPTN + o] = acc;
  }
  __syncthreads();
  if(tid==0){
    float mx = sacc[0]; int mi = 0;
    for(int o=1;o<OPTN;o++) if(sacc[o] > mx){ mx = sacc[o]; mi = o; }
    sbest = mi;
  }
  __syncthreads();
  if(tid < 4*SEQN){
    int c = tid/SEQN, t = tid%SEQN;
    int val = gg[((b*OPTN + sbest)*4 + c)*SEQN + t];
    out[OFF_TOPO + c*(BB*SEQN) + b*SEQN + t] = (float)val;
    if(c==0){ sym_i[b*SEQN + t] = val; ssym[t] = val; }
  }
  __syncthreads();
  // build A rows m=b*10+t : [emb[sym] | ts[b]] as bf16
  for(int idx = tid; idx < SEQN*D2; idx += 256){
    int t = idx >> 9, k = idx & 511;
    float val = (k < DD) ? emb[ssym[t]*DD + k] : ts[b*DD + (k-DD)];
    A[(size_t)(b*SEQN + t)*D2 + k] = f2bf(val);
  }
}

// passthrough outputs 0..2 as float
__global__ void k_pass(const int* __restrict__ lhs, const int* __restrict__ lhs_mask,
                       const int* __restrict__ gg, float* __restrict__ out){
  int i = blockIdx.x*256 + threadIdx.x;
  if(i < BB) out[i] = (float)lhs[i];
  else if(i < 2*BB) out[i] = (float)lhs_mask[i - BB];
  else if(i < 2*BB + BB*OPTN*4*SEQN) out[2*BB + (i - 2*BB)] = (float)gg[i - 2*BB];
}

// exact_logit: bf16 MFMA GEMM, M=2560 x N=10000, K=512, 128x128 tiles
// epilogue uses L2-resident bitmask instead of 100MB tok_table gather + logf
__global__ __launch_bounds__(256) void k_tok_mfma(
    const unsigned short* __restrict__ A, const unsigned short* __restrict__ Bw,
    const float* __restrict__ btok, const unsigned int* __restrict__ tokbits,
    const int* __restrict__ sym_i, float* __restrict__ out){
  __shared__ unsigned short As[128*40];
  __shared__ unsigned short Bs[128*40];
  __shared__ float sBtok[128];
  int tid = threadIdx.x;
  int lane = tid & 63, wave = tid >> 6;
  int c = lane & 15, q = lane >> 4;
  int wm = (wave >> 1)*64, wn = (wave & 1)*64;
  int m0 = blockIdx.y*128, n0 = blockIdx.x*128;
  if(tid < 128){
    int n = n0 + tid;
    sBtok[tid] = (n < VT) ? btok[n] : 0.f;
  }
  f32x4 acc[4][4];
  #pragma unroll
  for(int i=0;i<4;i++)
    #pragma unroll
    for(int j=0;j<4;j++) acc[i][j] = (f32x4){0.f,0.f,0.f,0.f};

  for(int k0=0;k0<D2;k0+=32){
    #pragma unroll
    for(int ci = tid; ci < 512; ci += 256){
      int row = ci >> 2, ko = (ci & 3)*8;
      float4 av = *(const float4*)(A + (size_t)(m0+row)*D2 + k0 + ko);
      *(float4*)(As + row*40 + ko) = av;
      int n = n0 + row;
      float4 bv = {0,0,0,0};
      if(n < VT) bv = *(const float4*)(Bw + (size_t)n*D2 + k0 + ko);
      *(float4*)(Bs + row*40 + ko) = bv;
    }
    __syncthreads();
    bf16x8 af[4], bf[4];
    #pragma unroll
    for(int i=0;i<4;i++) af[i] = *(const bf16x8*)(As + (wm + i*16 + c)*40 + q*8);
    #pragma unroll
    for(int j=0;j<4;j++) bf[j] = *(const bf16x8*)(Bs + (wn + j*16 + c)*40 + q*8);
    #pragma unroll
    for(int i=0;i<4;i++)
      #pragma unroll
      for(int j=0;j<4;j++)
        acc[i][j] = __builtin_amdgcn_mfma_f32_16x16x32_bf16(af[i], bf[j], acc[i][j], 0, 0, 0);
    __syncthreads();
  }
  #pragma unroll
  for(int i=0;i<4;i++){
    #pragma unroll
    for(int r=0;r<4;r++){
      int m = m0 + wm + i*16 + q*4 + r;
      int s = sym_i[m];
      const unsigned int* bt = tokbits + (size_t)s*TOKB_STRIDE;
      #pragma unroll
      for(int j=0;j<4;j++){
        int n = n0 + wn + j*16 + c;
        if(n < VT){
          unsigned int wb = bt[n >> 5];
          float add = ((wb >> (n & 31)) & 1u) ? 0.f : LOG_TINY;
          out[OFF_EXACT + (size_t)m*VT + n] = acc[i][j][r] + sBtok[n - n0] + add;
        }
      }
    }
  }
}

extern "C" void kernel_launch(void* const* d_in, const int* in_sizes, int n_in,
                              void* d_out, int out_size, void* d_ws, size_t ws_size,
                              hipStream_t stream) {
  const int*   lhs       = (const int*)  d_in[0];
  const int*   lhs_mask  = (const int*)  d_in[1];
  const float* tree_state= (const float*)d_in[2];
  const int*   gg        = (const int*)  d_in[3];
  const float* emb       = (const float*)d_in[4];
  const float* mem       = (const float*)d_in[5];
  const float* Wx        = (const float*)d_in[6];
  const float* Wh        = (const float*)d_in[7];
  const float* bx        = (const float*)d_in[8];
  const float* bh        = (const float*)d_in[9];
  const float* Wc        = (const float*)d_in[10];
  const float* bc        = (const float*)d_in[11];
  const float* Wsym      = (const float*)d_in[12];
  const float* bsym      = (const float*)d_in[13];
  const float* Wtok      = (const float*)d_in[14];
  const float* btok      = (const float*)d_in[15];
  const float* tok_table = (const float*)d_in[16];
  float* out = (float*)d_out;

  float* W    = (float*)d_ws;
  float* gh   = W;                        // 196608 floats
  float* ts   = gh  + BB*D3;              // 65536
  float* soa  = ts  + BB*DD;              // 65536
  float* cl   = soa + BB*DD;              // 5,120,000
  float* EW   = cl  + (size_t)SEQN*BB*VV; // 1,536,000
  int*   sym_i= (int*)(EW + VV*D3);       // 2560
  unsigned short* Abf  = (unsigned short*)(sym_i + BB*SEQN);  // 2560*512 ushorts
  unsigned short* WtokB= Abf + (size_t)BB*SEQN*D2;            // 10000*512 ushorts
  unsigned int* tokbits= (unsigned int*)(WtokB + (size_t)VT*D2); // 2000*320 uints

  hipMemcpyAsync(ts, tree_state, BB*DD*sizeof(float), hipMemcpyDeviceToDevice, stream);

  k_pass<<<(2*BB + BB*OPTN*4*SEQN + 255)/256, 256, 0, stream>>>(lhs, lhs_mask, gg, out);
  k_tokbits<<<dim3((VT+255)/256, VV), 256, 0, stream>>>(tok_table, tokbits);
  k_wtokT<<<dim3((VT+63)/64, D2/32), 256, 0, stream>>>(Wtok, WtokB);
  k_gh<<<dim3(BB,3), 256, 0, stream>>>(tree_state, Wh, bh, gh);
  k_ew<<<dim3(D3/64, (VV+63)/64), 256, 0, stream>>>(emb, Wx, EW);

  for(int t=0; t<SEQN; t++){
    const float* cl_prev = (t == 0) ? nullptr : (cl + (size_t)(t-1)*BB*VV);
    k_step<<<BB, 256, 0, stream>>>(cl_prev, lhs, EW, gh, bx, tree_state, mem, Wc, bc, soa, ts);
    k_clogits<<<dim3(32,4), 256, 0, stream>>>(soa, Wsym, bsym, gg, t, cl);
  }

  k_opts<<<BB, 256, 0, stream>>>(cl, gg, emb, ts, out, sym_i, Abf);
  k_tok_mfma<<<dim3((VT+127)/128, (BB*SEQN)/128), 256, 0, stream>>>(Abf, WtokB, btok, tokbits, sym_i, out);
}

// Round 2
// 879.561 us; speedup vs baseline: 1.2537x; 1.0254x over previous
//
#include <hip/hip_runtime.h>
#include <math.h>

#define BB 256
#define DD 256
#define VV 2000
#define VT 10000
#define OPTN 16
#define SEQN 10
#define SRCN 40
#define D3 768
#define D2 512

#define LOG_TINY (-29.9336062f)

// output offsets (floats)
#define OFF_OPTS  (2*BB + BB*OPTN*4*SEQN)          // 164352
#define OFF_TOPO  (OFF_OPTS + BB*OPTN)             // 168448
#define OFF_EXACT (OFF_TOPO + 4*BB*SEQN)           // 178688

// tok bitmask: 2000 rows x 320 dwords (10240 bits >= 10000)
#define TOKB_STRIDE 320
#define TOKB_W 313   // used dwords per row (ceil(10000/32))

typedef __bf16 bf16x8 __attribute__((ext_vector_type(8)));
typedef float  f32x4  __attribute__((ext_vector_type(4)));

__device__ __forceinline__ float sigm(float x){ return 1.0f/(1.0f+expf(-x)); }
__device__ __forceinline__ unsigned short f2bf(float x){
  union { float f; unsigned int u; } v; v.f = x;
  unsigned int r = (v.u + 0x7FFF + ((v.u >> 16) & 1)) >> 16;
  return (unsigned short)r;
}

// gh = tree_state @ Wh + bh  (constant across steps: gru uses outer tree_state)
__global__ void k_gh(const float* __restrict__ ts0, const float* __restrict__ Wh,
                     const float* __restrict__ bh, float* __restrict__ gh){
  int b = blockIdx.x;
  int j = blockIdx.y*256 + threadIdx.x;
  __shared__ float hsh[DD];
  hsh[threadIdx.x] = ts0[b*DD + threadIdx.x];
  __syncthreads();
  float a0 = bh[j], a1 = 0.f, a2 = 0.f, a3 = 0.f;
  #pragma unroll 4
  for(int k=0;k<DD;k+=4){
    a0 = fmaf(hsh[k+0], Wh[(k+0)*D3 + j], a0);
    a1 = fmaf(hsh[k+1], Wh[(k+1)*D3 + j], a1);
    a2 = fmaf(hsh[k+2], Wh[(k+2)*D3 + j], a2);
    a3 = fmaf(hsh[k+3], Wh[(k+3)*D3 + j], a3);
  }
  gh[b*D3 + j] = (a0+a1)+(a2+a3);
}

// EW = emb @ Wx  (2000 x 768, K=256) fp32 64x64 tiler
__global__ void k_ew(const float* __restrict__ emb, const float* __restrict__ Wx,
                     float* __restrict__ EW){
  __shared__ float As[16][64];
  __shared__ float Bs[16][64];
  int tid = threadIdx.x;
  int tx = tid & 15, ty = tid >> 4;
  int m0 = blockIdx.y*64, n0 = blockIdx.x*64;
  float acc[4][4];
  #pragma unroll
  for(int i=0;i<4;i++){ acc[i][0]=0.f; acc[i][1]=0.f; acc[i][2]=0.f; acc[i][3]=0.f; }
  for(int k0=0;k0<DD;k0+=16){
    {
      int row = tid >> 2, kk = (tid & 3)*4;
      int m = m0 + row;
      float4 av = {0,0,0,0};
      if(m < VV) av = *(const float4*)&emb[m*DD + k0 + kk];
      As[kk+0][row]=av.x; As[kk+1][row]=av.y; As[kk+2][row]=av.z; As[kk+3][row]=av.w;
    }
    {
      int r = tid >> 4, c2 = (tid & 15)*4;
      float4 bv = *(const float4*)&Wx[(k0+r)*D3 + n0 + c2];
      *(float4*)&Bs[r][c2] = bv;
    }
    __syncthreads();
    #pragma unroll
    for(int k=0;k<16;k++){
      float4 a4 = *(const float4*)&As[k][ty*4];
      float4 b4 = *(const float4*)&Bs[k][tx*4];
      float av[4] = {a4.x,a4.y,a4.z,a4.w};
      float bw[4] = {b4.x,b4.y,b4.z,b4.w};
      #pragma unroll
      for(int i=0;i<4;i++)
        #pragma unroll
        for(int j=0;j<4;j++) acc[i][j] = fmaf(av[i], bw[j], acc[i][j]);
    }
    __syncthreads();
  }
  #pragma unroll
  for(int i=0;i<4;i++){
    int m = m0 + ty*4 + i;
    if(m < VV){
      #pragma unroll
      for(int j=0;j<4;j++) EW[m*D3 + n0 + tx*4 + j] = acc[i][j];
    }
  }
}

// Wtok [512][10000] fp32 -> WtokB [10000][512] bf16 (transpose + convert)
__global__ void k_wtokT(const float* __restrict__ Wtok, unsigned short* __restrict__ WtokB){
  __shared__ float tile[32][65];
  int tid = threadIdx.x;
  int n0 = blockIdx.x*64, k0 = blockIdx.y*32;
  #pragma unroll
  for(int p=0;p<8;p++){
    int idx = tid + p*256;
    int kk = idx >> 6, nn = idx & 63;
    int n = n0 + nn;
    tile[kk][nn] = (n < VT) ? Wtok[(size_t)(k0+kk)*VT + n] : 0.f;
  }
  __syncthreads();
  #pragma unroll
  for(int p=0;p<4;p++){
    int idx = tid + p*256;
    int nn = idx >> 4, kk = (idx & 15)*2;
    int n = n0 + nn;
    if(n < VT){
      ushort2 v;
      v.x = f2bf(tile[kk][nn]);
      v.y = f2bf(tile[kk+1][nn]);
      *(ushort2*)&WtokB[(size_t)n*D2 + k0 + kk] = v;
    }
  }
}

// tok_table (binary 0/1) -> bitmask, 1 bit per entry. log(tt+1e-13) is EXACTLY
// (tt ? 0 : LOG_TINY) in fp32. Grid-stride, float4 loads, 1 dword out/thread.
__global__ __launch_bounds__(256) void k_tokbits(const float* __restrict__ tok_table,
                                                 unsigned int* __restrict__ bits){
  int idx = blockIdx.x*256 + threadIdx.x;
  const int total = VV*TOKB_W;
  for(; idx < total; idx += gridDim.x*256){
    int v = idx / TOKB_W, w = idx - v*TOKB_W;
    const float* row = tok_table + (size_t)v*VT + w*32;
    unsigned int bv = 0;
    if(w*32 + 32 <= VT){
      #pragma unroll
      for(int k=0;k<8;k++){
        float4 x = *(const float4*)(row + k*4);
        bv |= (x.x>0.5f?1u:0u) << (k*4+0);
        bv |= (x.y>0.5f?1u:0u) << (k*4+1);
        bv |= (x.z>0.5f?1u:0u) << (k*4+2);
        bv |= (x.w>0.5f?1u:0u) << (k*4+3);
      }
    } else {
      for(int k=0;k<32;k++){
        int n = w*32 + k;
        if(n < VT && row[k] > 0.5f) bv |= 1u << k;
      }
    }
    bits[v*TOKB_STRIDE + w] = bv;
  }
}

// fused per-step: argmax(cl[t-1]) -> sym; gates from EW gather; gru; attention;
// soa=tanh([ctx,h]@Wc+bc); ts update
__global__ void k_step(const float* __restrict__ cl_prev, const int* __restrict__ lhs,
                       const float* __restrict__ EW, const float* __restrict__ gh,
                       const float* __restrict__ bx, const float* __restrict__ ts0,
                       const float* __restrict__ mem, const float* __restrict__ Wc,
                       const float* __restrict__ bc, float* __restrict__ soa,
                       float* __restrict__ ts){
  int b = blockIdx.x, tid = threadIdx.x;
  int lane = tid & 63, wv = tid >> 6;
  __shared__ float hs[DD], cs[DD], sc[SRCN];
  __shared__ float smx[4]; __shared__ int smi[4];
  __shared__ int sym_sh;
  int sym;
  if(cl_prev){
    const float* row = cl_prev + (size_t)b*VV;
    float mx = -1e30f; int mi = 0;
    for(int v=tid; v<VV; v+=256){
      float val = row[v];
      if(val > mx){ mx = val; mi = v; }
    }
    // wave butterfly argmax (tie: smaller index)
    for(int off=32; off; off>>=1){
      float ov = __shfl_xor(mx, off, 64);
      int   oi = __shfl_xor(mi, off, 64);
      if(ov > mx || (ov == mx && oi < mi)){ mx = ov; mi = oi; }
    }
    if(lane==0){ smx[wv]=mx; smi[wv]=mi; }
    __syncthreads();
    if(tid==0){
      float bmx = smx[0]; int bmi = smi[0];
      for(int w=1;w<4;w++){
        if(smx[w] > bmx || (smx[w]==bmx && smi[w] < bmi)){ bmx=smx[w]; bmi=smi[w]; }
      }
      sym_sh = bmi;
    }
    __syncthreads();
    sym = sym_sh;
  } else {
    sym = lhs[b];
  }
  const float* ew = EW + sym*D3;
  const float* ghb = gh + b*D3;
  float r = sigm(ew[tid]     + bx[tid]     + ghb[tid]);
  float z = sigm(ew[256+tid] + bx[256+tid] + ghb[256+tid]);
  float n = tanhf(ew[512+tid] + bx[512+tid] + r*ghb[512+tid]);
  float h = (1.0f - z)*n + z*ts0[b*DD + tid];
  hs[tid] = h;
  __syncthreads();
  for(int s = wv; s < SRCN; s += 4){
    float p = 0.f;
    const float* mrow = mem + (size_t)(b*SRCN + s)*DD;
    #pragma unroll 4
    for(int d = lane; d < DD; d += 64) p = fmaf(hs[d], mrow[d], p);
    for(int off=32; off; off>>=1) p += __shfl_down(p, off, 64);
    if(lane==0) sc[s] = p;
  }
  __syncthreads();
  // wave-parallel softmax over the 40 scores (first wave only)
  if(tid < 64){
    float v = (tid < SRCN) ? sc[tid] : -1e30f;
    float mx = v;
    for(int off=32; off; off>>=1) mx = fmaxf(mx, __shfl_xor(mx, off, 64));
    float e = (tid < SRCN) ? expf(v - mx) : 0.f;
    float sum = e;
    for(int off=32; off; off>>=1) sum += __shfl_xor(sum, off, 64);
    if(tid < SRCN) sc[tid] = e / sum;
  }
  __syncthreads();
  float c = 0.f;
  #pragma unroll 8
  for(int s=0;s<SRCN;s++) c = fmaf(sc[s], mem[(size_t)(b*SRCN+s)*DD + tid], c);
  cs[tid] = c;
  __syncthreads();
  // [ctx|h] @ Wc — 8 independent accumulators (latency-exposed at 1 block/CU)
  float a0 = bc[tid], a1=0.f, a2=0.f, a3=0.f, a4=0.f, a5=0.f, a6=0.f, a7=0.f;
  #pragma unroll 4
  for(int k=0;k<DD;k+=8){
    a0 = fmaf(cs[k+0], Wc[(k+0)*DD + tid], a0);
    a1 = fmaf(cs[k+1], Wc[(k+1)*DD + tid], a1);
    a2 = fmaf(cs[k+2], Wc[(k+2)*DD + tid], a2);
    a3 = fmaf(cs[k+3], Wc[(k+3)*DD + tid], a3);
    a4 = fmaf(cs[k+4], Wc[(k+4)*DD + tid], a4);
    a5 = fmaf(cs[k+5], Wc[(k+5)*DD + tid], a5);
    a6 = fmaf(cs[k+6], Wc[(k+6)*DD + tid], a6);
    a7 = fmaf(cs[k+7], Wc[(k+7)*DD + tid], a7);
  }
  #pragma unroll 4
  for(int k=0;k<DD;k+=8){
    a0 = fmaf(hs[k+0], Wc[(k+0+DD)*DD + tid], a0);
    a1 = fmaf(hs[k+1], Wc[(k+1+DD)*DD + tid], a1);
    a2 = fmaf(hs[k+2], Wc[(k+2+DD)*DD + tid], a2);
    a3 = fmaf(hs[k+3], Wc[(k+3+DD)*DD + tid], a3);
    a4 = fmaf(hs[k+4], Wc[(k+4+DD)*DD + tid], a4);
    a5 = fmaf(hs[k+5], Wc[(k+5+DD)*DD + tid], a5);
    a6 = fmaf(hs[k+6], Wc[(k+6+DD)*DD + tid], a6);
    a7 = fmaf(hs[k+7], Wc[(k+7+DD)*DD + tid], a7);
  }
  float sv = tanhf(((a0+a1)+(a2+a3)) + ((a4+a5)+(a6+a7)));
  soa[b*DD + tid] = sv;
  ts[b*DD + tid] = tanhf(ts[b*DD + tid] + sv);
}

// clogits[t][b][v] = soa[b]@Wsym[:,v] + bsym[v] + (allowed? 0 : LOG_TINY)
// allowed-mask via per-row 64-bit LDS bitmask (replaces 16 compares/output)
__global__ void k_clogits(const float* __restrict__ A, const float* __restrict__ Wsym,
                          const float* __restrict__ bsym, const int* __restrict__ gg,
                          int t, float* __restrict__ cl){
  __shared__ float As[16][64];
  __shared__ float Bs[16][64];
  __shared__ unsigned int selb[64][2];
  int tid = threadIdx.x;
  int tx = tid & 15, ty = tid >> 4;
  int m0 = blockIdx.y*64, n0 = blockIdx.x*64;
  if(tid < 128) selb[tid>>1][tid&1] = 0u;
  __syncthreads();
  for(int idx = tid; idx < 64*OPTN; idx += 256){
    int i = idx >> 4, o = idx & 15;
    int bb = m0 + i;
    int base = ((bb*OPTN + o)*4)*SEQN + t;
    int mk = gg[base + 3*SEQN];
    int v = mk ? gg[base] : -1;
    unsigned int d = (unsigned int)(v - n0);
    if(d < 64u) atomicOr(&selb[i][d>>5], 1u << (d&31));
  }
  float acc[4][4];
  #pragma unroll
  for(int i=0;i<4;i++){ acc[i][0]=0.f; acc[i][1]=0.f; acc[i][2]=0.f; acc[i][3]=0.f; }
  for(int k0=0;k0<DD;k0+=16){
    {
      int row = tid >> 2, kk = (tid & 3)*4;
      float4 av = *(const float4*)&A[(m0+row)*DD + k0 + kk];
      As[kk+0][row]=av.x; As[kk+1][row]=av.y; As[kk+2][row]=av.z; As[kk+3][row]=av.w;
    }
    {
      int r = tid >> 4, c2 = (tid & 15)*4;
      int n = n0 + c2;
      float4 bv;
      if(n + 3 < VV){ bv = *(const float4*)&Wsym[(k0+r)*VV + n]; }
      else {
        bv.x = (n+0<VV)? Wsym[(k0+r)*VV + n+0] : 0.f;
        bv.y = (n+1<VV)? Wsym[(k0+r)*VV + n+1] : 0.f;
        bv.z = (n+2<VV)? Wsym[(k0+r)*VV + n+2] : 0.f;
        bv.w = (n+3<VV)? Wsym[(k0+r)*VV + n+3] : 0.f;
      }
      *(float4*)&Bs[r][c2] = bv;
    }
    __syncthreads();
    #pragma unroll
    for(int k=0;k<16;k++){
      float4 a4 = *(const float4*)&As[k][ty*4];
      float4 b4 = *(const float4*)&Bs[k][tx*4];
      float av[4] = {a4.x,a4.y,a4.z,a4.w};
      float bw[4] = {b4.x,b4.y,b4.z,b4.w};
      #pragma unroll
      for(int i=0;i<4;i++)
        #pragma unroll
        for(int j=0;j<4;j++) acc[i][j] = fmaf(av[i], bw[j], acc[i][j]);
    }
    __syncthreads();
  }
  #pragma unroll
  for(int i=0;i<4;i++){
    int m = m0 + ty*4 + i;
    unsigned int s0 = selb[ty*4+i][0], s1 = selb[ty*4+i][1];
    #pragma unroll
    for(int j=0;j<4;j++){
      int n = n0 + tx*4 + j;
      if(n < VV){
        int nn = tx*4 + j;
        unsigned int wb = (nn < 32) ? s0 : s1;
        float add = ((wb >> (nn & 31)) & 1u) ? 0.f : LOG_TINY;
        cl[((size_t)t*BB + m)*VV + n] = acc[i][j] + bsym[n] + add;
      }
    }
  }
}

// per-b: lse for all t; opts_logp; best; topo outputs; sym_i; build bf16 A rows
__global__ void k_opts(const float* __restrict__ cl, const int* __restrict__ gg,
                       const float* __restrict__ emb, const float* __restrict__ ts,
                       float* __restrict__ out, int* __restrict__ sym_i,
                       unsigned short* __restrict__ A){
  int b = blockIdx.x, tid = threadIdx.x;
  int lane = tid & 63, wv = tid >> 6;
  __shared__ float redm[4], reds[4];
  __shared__ float lse_sh[SEQN];
  __shared__ float sacc[OPTN];
  __shared__ int ssym[SEQN];
  __shared__ int sbest;
  for(int t=0;t<SEQN;t++){
    const float* row = cl + ((size_t)t*BB + b)*VV;
    float mx = -1e30f;
    for(int v=tid; v<VV; v+=256) mx = fmaxf(mx, row[v]);
    for(int off=32; off; off>>=1) mx = fmaxf(mx, __shfl_xor(mx, off, 64));
    if(lane==0) redm[wv] = mx;
    __syncthreads();
    float gmx = fmaxf(fmaxf(redm[0],redm[1]), fmaxf(redm[2],redm[3]));
    float sum = 0.f;
    for(int v=tid; v<VV; v+=256) sum += expf(row[v]-gmx);
    for(int off=32; off; off>>=1) sum += __shfl_xor(sum, off, 64);
    if(lane==0) reds[wv] = sum;
    __syncthreads();
    if(tid==0) lse_sh[t] = gmx + logf(reds[0]+reds[1]+reds[2]+reds[3]);
    __syncthreads();
  }
  if(tid < OPTN){
    int o = tid;
    float acc = 0.f;
    for(int t=0;t<SEQN;t++){
      int base = ((b*OPTN + o)*4)*SEQN + t;
      int mk = gg[base + 3*SEQN];
      if(mk){
        int v = gg[base];
        float p = expf(cl[((size_t)t*BB + b)*VV + v] - lse_sh[t]);
        acc += logf(p + 1e-13f);
      }
    }
    sacc[o] = acc;
    out[OFF_OPTS + b*OPTN + o] = acc;
  }
  __syncthreads();
  if(tid==0){
    float mx = sacc[0]; int mi = 0;
    for(int o=1;o<OPTN;o++) if(sacc[o] > mx){ mx = sacc[o]; mi = o; }
    sbest = mi;
  }
  __syncthreads();
  if(tid < 4*SEQN){
    int c = tid/SEQN, t = tid%SEQN;
    int val = gg[((b*OPTN + sbest)*4 + c)*SEQN + t];
    out[OFF_TOPO + c*(BB*SEQN) + b*SEQN + t] = (float)val;
    if(c==0){ sym_i[b*SEQN + t] = val; ssym[t] = val; }
  }
  __syncthreads();
  // build A rows m=b*10+t : [emb[sym] | ts[b]] as bf16
  for(int idx = tid; idx < SEQN*D2; idx += 256){
    int t = idx >> 9, k = idx & 511;
    float val = (k < DD) ? emb[ssym[t]*DD + k] : ts[b*DD + (k-DD)];
    A[(size_t)(b*SEQN + t)*D2 + k] = f2bf(val);
  }
}

// passthrough outputs 0..2 as float
__global__ void k_pass(const int* __restrict__ lhs, const int* __restrict__ lhs_mask,
                       const int* __restrict__ gg, float* __restrict__ out){
  int i = blockIdx.x*256 + threadIdx.x;
  if(i < BB) out[i] = (float)lhs[i];
  else if(i < 2*BB) out[i] = (float)lhs_mask[i - BB];
  else if(i < 2*BB + BB*OPTN*4*SEQN) out[2*BB + (i - 2*BB)] = (float)gg[i - 2*BB];
}

// exact_logit: bf16 MFMA GEMM, M=2560 x N=10000, K=512, 128x128 tiles
// epilogue: per-wave LDS transpose of C -> coalesced float4 stores
__global__ __launch_bounds__(256) void k_tok_mfma(
    const unsigned short* __restrict__ A, const unsigned short* __restrict__ Bw,
    const float* __restrict__ btok, const unsigned int* __restrict__ tokbits,
    const int* __restrict__ sym_i, float* __restrict__ out){
  // As = Ssh[0..], Bs = Ssh[5120..]; epilogue reuses Ssh as float staging
  __shared__ __align__(16) unsigned short Ssh[2*128*40];
  __shared__ float sBtok[128];
  unsigned short* As = Ssh;
  unsigned short* Bs = Ssh + 128*40;
  int tid = threadIdx.x;
  int lane = tid & 63, wave = tid >> 6;
  int c = lane & 15, q = lane >> 4;
  int wm = (wave >> 1)*64, wn = (wave & 1)*64;
  int m0 = blockIdx.y*128, n0 = blockIdx.x*128;
  if(tid < 128){
    int n = n0 + tid;
    sBtok[tid] = (n < VT) ? btok[n] : 0.f;
  }
  f32x4 acc[4][4];
  #pragma unroll
  for(int i=0;i<4;i++)
    #pragma unroll
    for(int j=0;j<4;j++) acc[i][j] = (f32x4){0.f,0.f,0.f,0.f};

  for(int k0=0;k0<D2;k0+=32){
    #pragma unroll
    for(int ci = tid; ci < 512; ci += 256){
      int row = ci >> 2, ko = (ci & 3)*8;
      float4 av = *(const float4*)(A + (size_t)(m0+row)*D2 + k0 + ko);
      *(float4*)(As + row*40 + ko) = av;
      int n = n0 + row;
      float4 bv = {0,0,0,0};
      if(n < VT) bv = *(const float4*)(Bw + (size_t)n*D2 + k0 + ko);
      *(float4*)(Bs + row*40 + ko) = bv;
    }
    __syncthreads();
    bf16x8 af[4], bf[4];
    #pragma unroll
    for(int i=0;i<4;i++) af[i] = *(const bf16x8*)(As + (wm + i*16 + c)*40 + q*8);
    #pragma unroll
    for(int j=0;j<4;j++) bf[j] = *(const bf16x8*)(Bs + (wn + j*16 + c)*40 + q*8);
    #pragma unroll
    for(int i=0;i<4;i++)
      #pragma unroll
      for(int j=0;j<4;j++)
        acc[i][j] = __builtin_amdgcn_mfma_f32_16x16x32_bf16(af[i], bf[j], acc[i][j], 0, 0, 0);
    __syncthreads();
  }
  // ---- epilogue: per-wave 16x64 chunk transpose through LDS, float4 stores ----
  // per-wave staging region: 64 cols x 20 (16 rows + pad), col-major. 5 KB/wave.
  float* sw = (float*)Ssh + wave*(64*20);
  int lrow = lane >> 2, ln4 = lane & 3;
  int srow[4];
  #pragma unroll
  for(int i=0;i<4;i++) srow[i] = sym_i[m0 + wm + i*16 + lrow];
  #pragma unroll
  for(int i=0;i<4;i++){
    // write: thread holds rows q*4+0..3 (contiguous in col-major) at col j*16+c
    #pragma unroll
    for(int j=0;j<4;j++)
      *(f32x4*)(sw + (j*16 + c)*20 + q*4) = acc[i][j];
    int row_g = m0 + wm + i*16 + lrow;
    const unsigned int* bt = tokbits + (size_t)srow[i]*TOKB_STRIDE;
    float* orow = out + OFF_EXACT + (size_t)row_g*VT;
    #pragma unroll
    for(int s4=0;s4<4;s4++){
      int colo = ln4*4 + s4*16;           // multiple of 4, 0..60
      int n = n0 + wn + colo;
      if(n < VT){
        float4 bt4 = *(const float4*)&sBtok[wn + colo];
        unsigned int wb = bt[n >> 5];
        int sh = n & 31;
        float4 o;
        o.x = sw[(colo+0)*20 + lrow] + bt4.x + (((wb>>(sh+0))&1u) ? 0.f : LOG_TINY);
        o.y = sw[(colo+1)*20 + lrow] + bt4.y + (((wb>>(sh+1))&1u) ? 0.f : LOG_TINY);
        o.z = sw[(colo+2)*20 + lrow] + bt4.z + (((wb>>(sh+2))&1u) ? 0.f : LOG_TINY);
        o.w = sw[(colo+3)*20 + lrow] + bt4.w + (((wb>>(sh+3))&1u) ? 0.f : LOG_TINY);
        *(float4*)(orow + n) = o;
      }
    }
  }
}

extern "C" void kernel_launch(void* const* d_in, const int* in_sizes, int n_in,
                              void* d_out, int out_size, void* d_ws, size_t ws_size,
                              hipStream_t stream) {
  const int*   lhs       = (const int*)  d_in[0];
  const int*   lhs_mask  = (const int*)  d_in[1];
  const float* tree_state= (const float*)d_in[2];
  const int*   gg        = (const int*)  d_in[3];
  const float* emb       = (const float*)d_in[4];
  const float* mem       = (const float*)d_in[5];
  const float* Wx        = (const float*)d_in[6];
  const float* Wh        = (const float*)d_in[7];
  const float* bx        = (const float*)d_in[8];
  const float* bh        = (const float*)d_in[9];
  const float* Wc        = (const float*)d_in[10];
  const float* bc        = (const float*)d_in[11];
  const float* Wsym      = (const float*)d_in[12];
  const float* bsym      = (const float*)d_in[13];
  const float* Wtok      = (const float*)d_in[14];
  const float* btok      = (const float*)d_in[15];
  const float* tok_table = (const float*)d_in[16];
  float* out = (float*)d_out;

  float* W    = (float*)d_ws;
  float* gh   = W;                        // 196608 floats
  float* ts   = gh  + BB*D3;              // 65536
  float* soa  = ts  + BB*DD;              // 65536
  float* cl   = soa + BB*DD;              // 5,120,000
  float* EW   = cl  + (size_t)SEQN*BB*VV; // 1,536,000
  int*   sym_i= (int*)(EW + VV*D3);       // 2560
  unsigned short* Abf  = (unsigned short*)(sym_i + BB*SEQN);  // 2560*512 ushorts
  unsigned short* WtokB= Abf + (size_t)BB*SEQN*D2;            // 10000*512 ushorts
  unsigned int* tokbits= (unsigned int*)(WtokB + (size_t)VT*D2); // 2000*320 uints

  hipMemcpyAsync(ts, tree_state, BB*DD*sizeof(float), hipMemcpyDeviceToDevice, stream);

  k_pass<<<(2*BB + BB*OPTN*4*SEQN + 255)/256, 256, 0, stream>>>(lhs, lhs_mask, gg, out);
  k_tokbits<<<2048, 256, 0, stream>>>(tok_table, tokbits);
  k_wtokT<<<dim3((VT+63)/64, D2/32), 256, 0, stream>>>(Wtok, WtokB);
  k_gh<<<dim3(BB,3), 256, 0, stream>>>(tree_state, Wh, bh, gh);
  k_ew<<<dim3(D3/64, (VV+63)/64), 256, 0, stream>>>(emb, Wx, EW);

  for(int t=0; t<SEQN; t++){
    const float* cl_prev = (t == 0) ? nullptr : (cl + (size_t)(t-1)*BB*VV);
    k_step<<<BB, 256, 0, stream>>>(cl_prev, lhs, EW, gh, bx, tree_state, mem, Wc, bc, soa, ts);
    k_clogits<<<dim3(32,4), 256, 0, stream>>>(soa, Wsym, bsym, gg, t, cl);
  }

  k_opts<<<BB, 256, 0, stream>>>(cl, gg, emb, ts, out, sym_i, Abf);
  k_tok_mfma<<<dim3((VT+127)/128, (BB*SEQN)/128), 256, 0, stream>>>(Abf, WtokB, btok, tokbits, sym_i, out);
}

// Round 3
// 793.783 us; speedup vs baseline: 1.3892x; 1.1081x over previous
//
#include <hip/hip_runtime.h>
#include <math.h>

#define BB 256
#define DD 256
#define VV 2000
#define VT 10000
#define OPTN 16
#define SEQN 10
#define SRCN 40
#define D3 768
#define D2 512

#define LOG_TINY (-29.9336062f)

// output offsets (floats)
#define OFF_OPTS  (2*BB + BB*OPTN*4*SEQN)          // 164352
#define OFF_TOPO  (OFF_OPTS + BB*OPTN)             // 168448
#define OFF_EXACT (OFF_TOPO + 4*BB*SEQN)           // 178688

// tok bitmask: 2000 rows x 320 dwords (10240 bits >= 10000)
#define TOKB_STRIDE 320
#define TOKB_W 313   // used dwords per row (ceil(10000/32))

#define NWG_TOK 1580  // 79 n-blocks * 20 m-blocks

typedef __bf16 bf16x8 __attribute__((ext_vector_type(8)));
typedef float  f32x4  __attribute__((ext_vector_type(4)));

__device__ __forceinline__ float sigm(float x){ return 1.0f/(1.0f+expf(-x)); }
__device__ __forceinline__ unsigned short f2bf(float x){
  union { float f; unsigned int u; } v; v.f = x;
  unsigned int r = (v.u + 0x7FFF + ((v.u >> 16) & 1)) >> 16;
  return (unsigned short)r;
}

// gh = tree_state @ Wh + bh  (constant across steps: gru uses outer tree_state)
__global__ void k_gh(const float* __restrict__ ts0, const float* __restrict__ Wh,
                     const float* __restrict__ bh, float* __restrict__ gh){
  int b = blockIdx.x;
  int j = blockIdx.y*256 + threadIdx.x;
  __shared__ float hsh[DD];
  hsh[threadIdx.x] = ts0[b*DD + threadIdx.x];
  __syncthreads();
  float a0 = bh[j], a1 = 0.f, a2 = 0.f, a3 = 0.f;
  #pragma unroll 4
  for(int k=0;k<DD;k+=4){
    a0 = fmaf(hsh[k+0], Wh[(k+0)*D3 + j], a0);
    a1 = fmaf(hsh[k+1], Wh[(k+1)*D3 + j], a1);
    a2 = fmaf(hsh[k+2], Wh[(k+2)*D3 + j], a2);
    a3 = fmaf(hsh[k+3], Wh[(k+3)*D3 + j], a3);
  }
  gh[b*D3 + j] = (a0+a1)+(a2+a3);
}

// EW = emb @ Wx  (2000 x 768, K=256) fp32 64x64 tiler
__global__ void k_ew(const float* __restrict__ emb, const float* __restrict__ Wx,
                     float* __restrict__ EW){
  __shared__ float As[16][64];
  __shared__ float Bs[16][64];
  int tid = threadIdx.x;
  int tx = tid & 15, ty = tid >> 4;
  int m0 = blockIdx.y*64, n0 = blockIdx.x*64;
  float acc[4][4];
  #pragma unroll
  for(int i=0;i<4;i++){ acc[i][0]=0.f; acc[i][1]=0.f; acc[i][2]=0.f; acc[i][3]=0.f; }
  for(int k0=0;k0<DD;k0+=16){
    {
      int row = tid >> 2, kk = (tid & 3)*4;
      int m = m0 + row;
      float4 av = {0,0,0,0};
      if(m < VV) av = *(const float4*)&emb[m*DD + k0 + kk];
      As[kk+0][row]=av.x; As[kk+1][row]=av.y; As[kk+2][row]=av.z; As[kk+3][row]=av.w;
    }
    {
      int r = tid >> 4, c2 = (tid & 15)*4;
      float4 bv = *(const float4*)&Wx[(k0+r)*D3 + n0 + c2];
      *(float4*)&Bs[r][c2] = bv;
    }
    __syncthreads();
    #pragma unroll
    for(int k=0;k<16;k++){
      float4 a4 = *(const float4*)&As[k][ty*4];
      float4 b4 = *(const float4*)&Bs[k][tx*4];
      float av[4] = {a4.x,a4.y,a4.z,a4.w};
      float bw[4] = {b4.x,b4.y,b4.z,b4.w};
      #pragma unroll
      for(int i=0;i<4;i++)
        #pragma unroll
        for(int j=0;j<4;j++) acc[i][j] = fmaf(av[i], bw[j], acc[i][j]);
    }
    __syncthreads();
  }
  #pragma unroll
  for(int i=0;i<4;i++){
    int m = m0 + ty*4 + i;
    if(m < VV){
      #pragma unroll
      for(int j=0;j<4;j++) EW[m*D3 + n0 + tx*4 + j] = acc[i][j];
    }
  }
}

// Wtok [512][10000] fp32 -> WtokB [10000][512] bf16 (transpose + convert)
__global__ void k_wtokT(const float* __restrict__ Wtok, unsigned short* __restrict__ WtokB){
  __shared__ float tile[32][65];
  int tid = threadIdx.x;
  int n0 = blockIdx.x*64, k0 = blockIdx.y*32;
  #pragma unroll
  for(int p=0;p<8;p++){
    int idx = tid + p*256;
    int kk = idx >> 6, nn = idx & 63;
    int n = n0 + nn;
    tile[kk][nn] = (n < VT) ? Wtok[(size_t)(k0+kk)*VT + n] : 0.f;
  }
  __syncthreads();
  #pragma unroll
  for(int p=0;p<4;p++){
    int idx = tid + p*256;
    int nn = idx >> 4, kk = (idx & 15)*2;
    int n = n0 + nn;
    if(n < VT){
      ushort2 v;
      v.x = f2bf(tile[kk][nn]);
      v.y = f2bf(tile[kk+1][nn]);
      *(ushort2*)&WtokB[(size_t)n*D2 + k0 + kk] = v;
    }
  }
}

// tok_table (binary 0/1) -> bitmask, 1 bit per entry. log(tt+1e-13) is EXACTLY
// (tt ? 0 : LOG_TINY) in fp32. Grid-stride, float4 loads, 1 dword out/thread.
__global__ __launch_bounds__(256) void k_tokbits(const float* __restrict__ tok_table,
                                                 unsigned int* __restrict__ bits){
  int idx = blockIdx.x*256 + threadIdx.x;
  const int total = VV*TOKB_W;
  for(; idx < total; idx += gridDim.x*256){
    int v = idx / TOKB_W, w = idx - v*TOKB_W;
    const float* row = tok_table + (size_t)v*VT + w*32;
    unsigned int bv = 0;
    if(w*32 + 32 <= VT){
      #pragma unroll
      for(int k=0;k<8;k++){
        float4 x = *(const float4*)(row + k*4);
        bv |= (x.x>0.5f?1u:0u) << (k*4+0);
        bv |= (x.y>0.5f?1u:0u) << (k*4+1);
        bv |= (x.z>0.5f?1u:0u) << (k*4+2);
        bv |= (x.w>0.5f?1u:0u) << (k*4+3);
      }
    } else {
      for(int k=0;k<32;k++){
        int n = w*32 + k;
        if(n < VT && row[k] > 0.5f) bv |= 1u << k;
      }
    }
    bits[v*TOKB_STRIDE + w] = bv;
  }
}

// fused per-step: argmax(cl[t-1]) -> sym; gates from EW gather; gru; attention;
// soa=tanh([ctx,h]@Wc+bc); ts update
__global__ void k_step(const float* __restrict__ cl_prev, const int* __restrict__ lhs,
                       const float* __restrict__ EW, const float* __restrict__ gh,
                       const float* __restrict__ bx, const float* __restrict__ ts0,
                       const float* __restrict__ mem, const float* __restrict__ Wc,
                       const float* __restrict__ bc, float* __restrict__ soa,
                       float* __restrict__ ts){
  int b = blockIdx.x, tid = threadIdx.x;
  int lane = tid & 63, wv = tid >> 6;
  __shared__ float hs[DD], cs[DD], sc[SRCN];
  __shared__ float smx[4]; __shared__ int smi[4];
  __shared__ int sym_sh;
  int sym;
  if(cl_prev){
    const float* row = cl_prev + (size_t)b*VV;
    float mx = -1e30f; int mi = 0;
    for(int v=tid; v<VV; v+=256){
      float val = row[v];
      if(val > mx){ mx = val; mi = v; }
    }
    // wave butterfly argmax (tie: smaller index)
    for(int off=32; off; off>>=1){
      float ov = __shfl_xor(mx, off, 64);
      int   oi = __shfl_xor(mi, off, 64);
      if(ov > mx || (ov == mx && oi < mi)){ mx = ov; mi = oi; }
    }
    if(lane==0){ smx[wv]=mx; smi[wv]=mi; }
    __syncthreads();
    if(tid==0){
      float bmx = smx[0]; int bmi = smi[0];
      for(int w=1;w<4;w++){
        if(smx[w] > bmx || (smx[w]==bmx && smi[w] < bmi)){ bmx=smx[w]; bmi=smi[w]; }
      }
      sym_sh = bmi;
    }
    __syncthreads();
    sym = sym_sh;
  } else {
    sym = lhs[b];
  }
  const float* ew = EW + sym*D3;
  const float* ghb = gh + b*D3;
  float r = sigm(ew[tid]     + bx[tid]     + ghb[tid]);
  float z = sigm(ew[256+tid] + bx[256+tid] + ghb[256+tid]);
  float n = tanhf(ew[512+tid] + bx[512+tid] + r*ghb[512+tid]);
  float h = (1.0f - z)*n + z*ts0[b*DD + tid];
  hs[tid] = h;
  __syncthreads();
  for(int s = wv; s < SRCN; s += 4){
    float p = 0.f;
    const float* mrow = mem + (size_t)(b*SRCN + s)*DD;
    #pragma unroll 4
    for(int d = lane; d < DD; d += 64) p = fmaf(hs[d], mrow[d], p);
    for(int off=32; off; off>>=1) p += __shfl_down(p, off, 64);
    if(lane==0) sc[s] = p;
  }
  __syncthreads();
  // wave-parallel softmax over the 40 scores (first wave only)
  if(tid < 64){
    float v = (tid < SRCN) ? sc[tid] : -1e30f;
    float mx = v;
    for(int off=32; off; off>>=1) mx = fmaxf(mx, __shfl_xor(mx, off, 64));
    float e = (tid < SRCN) ? expf(v - mx) : 0.f;
    float sum = e;
    for(int off=32; off; off>>=1) sum += __shfl_xor(sum, off, 64);
    if(tid < SRCN) sc[tid] = e / sum;
  }
  __syncthreads();
  float c = 0.f;
  #pragma unroll 8
  for(int s=0;s<SRCN;s++) c = fmaf(sc[s], mem[(size_t)(b*SRCN+s)*DD + tid], c);
  cs[tid] = c;
  __syncthreads();
  // [ctx|h] @ Wc — 8 independent accumulators (latency-exposed at 1 block/CU)
  float a0 = bc[tid], a1=0.f, a2=0.f, a3=0.f, a4=0.f, a5=0.f, a6=0.f, a7=0.f;
  #pragma unroll 4
  for(int k=0;k<DD;k+=8){
    a0 = fmaf(cs[k+0], Wc[(k+0)*DD + tid], a0);
    a1 = fmaf(cs[k+1], Wc[(k+1)*DD + tid], a1);
    a2 = fmaf(cs[k+2], Wc[(k+2)*DD + tid], a2);
    a3 = fmaf(cs[k+3], Wc[(k+3)*DD + tid], a3);
    a4 = fmaf(cs[k+4], Wc[(k+4)*DD + tid], a4);
    a5 = fmaf(cs[k+5], Wc[(k+5)*DD + tid], a5);
    a6 = fmaf(cs[k+6], Wc[(k+6)*DD + tid], a6);
    a7 = fmaf(cs[k+7], Wc[(k+7)*DD + tid], a7);
  }
  #pragma unroll 4
  for(int k=0;k<DD;k+=8){
    a0 = fmaf(hs[k+0], Wc[(k+0+DD)*DD + tid], a0);
    a1 = fmaf(hs[k+1], Wc[(k+1+DD)*DD + tid], a1);
    a2 = fmaf(hs[k+2], Wc[(k+2+DD)*DD + tid], a2);
    a3 = fmaf(hs[k+3], Wc[(k+3+DD)*DD + tid], a3);
    a4 = fmaf(hs[k+4], Wc[(k+4+DD)*DD + tid], a4);
    a5 = fmaf(hs[k+5], Wc[(k+5+DD)*DD + tid], a5);
    a6 = fmaf(hs[k+6], Wc[(k+6+DD)*DD + tid], a6);
    a7 = fmaf(hs[k+7], Wc[(k+7+DD)*DD + tid], a7);
  }
  float sv = tanhf(((a0+a1)+(a2+a3)) + ((a4+a5)+(a6+a7)));
  soa[b*DD + tid] = sv;
  ts[b*DD + tid] = tanhf(ts[b*DD + tid] + sv);
}

// clogits[t][b][v] = soa[b]@Wsym[:,v] + bsym[v] + (allowed? 0 : LOG_TINY)
// 32x64 tiles -> 256 blocks (full GPU). allowed-mask via 64-bit LDS bitmask.
__global__ void k_clogits(const float* __restrict__ A, const float* __restrict__ Wsym,
                          const float* __restrict__ bsym, const int* __restrict__ gg,
                          int t, float* __restrict__ cl){
  __shared__ float As[16][32];
  __shared__ float Bs[16][64];
  __shared__ unsigned int selb[32][2];
  int tid = threadIdx.x;
  int tx = tid & 15, ty = tid >> 4;
  int m0 = blockIdx.y*32, n0 = blockIdx.x*64;
  if(tid < 64) selb[tid>>1][tid&1] = 0u;
  __syncthreads();
  for(int idx = tid; idx < 32*OPTN; idx += 256){
    int i = idx >> 4, o = idx & 15;
    int bb = m0 + i;
    int base = ((bb*OPTN + o)*4)*SEQN + t;
    int mk = gg[base + 3*SEQN];
    int v = mk ? gg[base] : -1;
    unsigned int d = (unsigned int)(v - n0);
    if(d < 64u) atomicOr(&selb[i][d>>5], 1u << (d&31));
  }
  float acc[2][4];
  #pragma unroll
  for(int i=0;i<2;i++){ acc[i][0]=0.f; acc[i][1]=0.f; acc[i][2]=0.f; acc[i][3]=0.f; }
  for(int k0=0;k0<DD;k0+=16){
    if(tid < 128){
      int row = tid >> 2, kk = (tid & 3)*4;
      float4 av = *(const float4*)&A[(m0+row)*DD + k0 + kk];
      As[kk+0][row]=av.x; As[kk+1][row]=av.y; As[kk+2][row]=av.z; As[kk+3][row]=av.w;
    }
    {
      int r = tid >> 4, c2 = (tid & 15)*4;
      int n = n0 + c2;
      float4 bv;
      if(n + 3 < VV){ bv = *(const float4*)&Wsym[(k0+r)*VV + n]; }
      else {
        bv.x = (n+0<VV)? Wsym[(k0+r)*VV + n+0] : 0.f;
        bv.y = (n+1<VV)? Wsym[(k0+r)*VV + n+1] : 0.f;
        bv.z = (n+2<VV)? Wsym[(k0+r)*VV + n+2] : 0.f;
        bv.w = (n+3<VV)? Wsym[(k0+r)*VV + n+3] : 0.f;
      }
      *(float4*)&Bs[r][c2] = bv;
    }
    __syncthreads();
    #pragma unroll
    for(int k=0;k<16;k++){
      float a0 = As[k][ty*2+0];
      float a1 = As[k][ty*2+1];
      float4 b4 = *(const float4*)&Bs[k][tx*4];
      acc[0][0] = fmaf(a0, b4.x, acc[0][0]);
      acc[0][1] = fmaf(a0, b4.y, acc[0][1]);
      acc[0][2] = fmaf(a0, b4.z, acc[0][2]);
      acc[0][3] = fmaf(a0, b4.w, acc[0][3]);
      acc[1][0] = fmaf(a1, b4.x, acc[1][0]);
      acc[1][1] = fmaf(a1, b4.y, acc[1][1]);
      acc[1][2] = fmaf(a1, b4.z, acc[1][2]);
      acc[1][3] = fmaf(a1, b4.w, acc[1][3]);
    }
    __syncthreads();
  }
  #pragma unroll
  for(int i=0;i<2;i++){
    int m = m0 + ty*2 + i;
    unsigned int s0 = selb[ty*2+i][0], s1 = selb[ty*2+i][1];
    int nb = n0 + tx*4;
    if(nb + 3 < VV){
      float4 o;
      #pragma unroll
      for(int j=0;j<4;j++){
        int nn = tx*4 + j;
        unsigned int wb = (nn < 32) ? s0 : s1;
        ((float*)&o)[j] = acc[i][j] + bsym[nb+j] + (((wb >> (nn&31)) & 1u) ? 0.f : LOG_TINY);
      }
      *(float4*)&cl[((size_t)t*BB + m)*VV + nb] = o;
    } else {
      #pragma unroll
      for(int j=0;j<4;j++){
        int n = nb + j;
        if(n < VV){
          int nn = tx*4 + j;
          unsigned int wb = (nn < 32) ? s0 : s1;
          cl[((size_t)t*BB + m)*VV + n] = acc[i][j] + bsym[n] + (((wb >> (nn&31)) & 1u) ? 0.f : LOG_TINY);
        }
      }
    }
  }
}

// per-b: lse for all t; opts_logp; best; topo outputs; sym_i; build bf16 A rows
__global__ void k_opts(const float* __restrict__ cl, const int* __restrict__ gg,
                       const float* __restrict__ emb, const float* __restrict__ ts,
                       float* __restrict__ out, int* __restrict__ sym_i,
                       unsigned short* __restrict__ A){
  int b = blockIdx.x, tid = threadIdx.x;
  int lane = tid & 63, wv = tid >> 6;
  __shared__ float redm[4], reds[4];
  __shared__ float lse_sh[SEQN];
  __shared__ float sacc[OPTN];
  __shared__ int ssym[SEQN];
  __shared__ int sbest;
  for(int t=0;t<SEQN;t++){
    const float* row = cl + ((size_t)t*BB + b)*VV;
    float mx = -1e30f;
    for(int v=tid; v<VV; v+=256) mx = fmaxf(mx, row[v]);
    for(int off=32; off; off>>=1) mx = fmaxf(mx, __shfl_xor(mx, off, 64));
    if(lane==0) redm[wv] = mx;
    __syncthreads();
    float gmx = fmaxf(fmaxf(redm[0],redm[1]), fmaxf(redm[2],redm[3]));
    float sum = 0.f;
    for(int v=tid; v<VV; v+=256) sum += expf(row[v]-gmx);
    for(int off=32; off; off>>=1) sum += __shfl_xor(sum, off, 64);
    if(lane==0) reds[wv] = sum;
    __syncthreads();
    if(tid==0) lse_sh[t] = gmx + logf(reds[0]+reds[1]+reds[2]+reds[3]);
    __syncthreads();
  }
  if(tid < OPTN){
    int o = tid;
    float acc = 0.f;
    for(int t=0;t<SEQN;t++){
      int base = ((b*OPTN + o)*4)*SEQN + t;
      int mk = gg[base + 3*SEQN];
      if(mk){
        int v = gg[base];
        float p = expf(cl[((size_t)t*BB + b)*VV + v] - lse_sh[t]);
        acc += logf(p + 1e-13f);
      }
    }
    sacc[o] = acc;
    out[OFF_OPTS + b*OPTN + o] = acc;
  }
  __syncthreads();
  if(tid==0){
    float mx = sacc[0]; int mi = 0;
    for(int o=1;o<OPTN;o++) if(sacc[o] > mx){ mx = sacc[o]; mi = o; }
    sbest = mi;
  }
  __syncthreads();
  if(tid < 4*SEQN){
    int c = tid/SEQN, t = tid%SEQN;
    int val = gg[((b*OPTN + sbest)*4 + c)*SEQN + t];
    out[OFF_TOPO + c*(BB*SEQN) + b*SEQN + t] = (float)val;
    if(c==0){ sym_i[b*SEQN + t] = val; ssym[t] = val; }
  }
  __syncthreads();
  // build A rows m=b*10+t : [emb[sym] | ts[b]] as bf16
  for(int idx = tid; idx < SEQN*D2; idx += 256){
    int t = idx >> 9, k = idx & 511;
    float val = (k < DD) ? emb[ssym[t]*DD + k] : ts[b*DD + (k-DD)];
    A[(size_t)(b*SEQN + t)*D2 + k] = f2bf(val);
  }
}

// passthrough outputs 0..2 as float
__global__ void k_pass(const int* __restrict__ lhs, const int* __restrict__ lhs_mask,
                       const int* __restrict__ gg, float* __restrict__ out){
  int i = blockIdx.x*256 + threadIdx.x;
  if(i < BB) out[i] = (float)lhs[i];
  else if(i < 2*BB) out[i] = (float)lhs_mask[i - BB];
  else if(i < 2*BB + BB*OPTN*4*SEQN) out[2*BB + (i - 2*BB)] = (float)gg[i - 2*BB];
}

// exact_logit: bf16 MFMA GEMM, M=2560 x N=10000, K=512, 128x128 tiles.
// v3: XCD-swizzled 1D grid, double-buffered LDS (1 barrier/iter), register
// prefetch of next K-tile under MFMA, stride-21 scalar-write epilogue transpose.
__global__ __launch_bounds__(256) void k_tok_mfma(
    const unsigned short* __restrict__ A, const unsigned short* __restrict__ Bw,
    const float* __restrict__ btok, const unsigned int* __restrict__ tokbits,
    const int* __restrict__ sym_i, float* __restrict__ out){
  __shared__ __align__(16) unsigned short Ssh[4*5120];  // As0,Bs0,As1,Bs1 (40 KB)
  __shared__ float sBtok[128];
  int tid = threadIdx.x;
  int lane = tid & 63, wave = tid >> 6;
  int c = lane & 15, q = lane >> 4;
  int wm = (wave >> 1)*64, wn = (wave & 1)*64;

  // bijective XCD swizzle (8 XCDs), n-major ordering for B-panel L2 locality
  int id = blockIdx.x;
  int xcd = id & 7, off = id >> 3;
  const int qq = NWG_TOK >> 3, rr = NWG_TOK & 7;  // 197, 4
  int start = (xcd < rr) ? xcd*(qq+1) : rr*(qq+1) + (xcd-rr)*qq;
  int ord = start + off;
  int mb = ord % 20, nb = ord / 20;
  int m0 = mb*128, n0 = nb*128;

  if(tid < 128){
    int n = n0 + tid;
    sBtok[tid] = (n < VT) ? btok[n] : 0.f;
  }
  f32x4 acc[4][4];
  #pragma unroll
  for(int i=0;i<4;i++)
    #pragma unroll
    for(int j=0;j<4;j++) acc[i][j] = (f32x4){0.f,0.f,0.f,0.f};

  // staging mapping: thread -> 2 rows (arow, arow+64), 16B chunk ach
  int arow = tid >> 2;            // 0..63
  int ach  = (tid & 3) * 8;       // ushort offset (16 B)
  const size_t aoff0 = (size_t)(m0 + arow)*D2 + ach;
  const size_t aoff1 = (size_t)(m0 + 64 + arow)*D2 + ach;
  int bn0 = n0 + arow, bn1 = n0 + 64 + arow;
  bool b0ok = bn0 < VT, b1ok = bn1 < VT;
  const size_t boff0 = (size_t)bn0*D2 + ach;
  const size_t boff1 = (size_t)bn1*D2 + ach;
  const float4 f0 = {0.f,0.f,0.f,0.f};

  float4 ra0 = *(const float4*)(A + aoff0);
  float4 ra1 = *(const float4*)(A + aoff1);
  float4 rb0 = b0ok ? *(const float4*)(Bw + boff0) : f0;
  float4 rb1 = b1ok ? *(const float4*)(Bw + boff1) : f0;

  for(int t=0; t<16; t++){
    unsigned short* As = Ssh + (t&1)*10240;
    unsigned short* Bs = As + 5120;
    *(float4*)(As + arow*40 + ach)      = ra0;
    *(float4*)(As + (64+arow)*40 + ach) = ra1;
    *(float4*)(Bs + arow*40 + ach)      = rb0;
    *(float4*)(Bs + (64+arow)*40 + ach) = rb1;
    __syncthreads();
    if(t < 15){
      int k0 = (t+1)*32;
      ra0 = *(const float4*)(A + aoff0 + k0);
      ra1 = *(const float4*)(A + aoff1 + k0);
      if(b0ok) rb0 = *(const float4*)(Bw + boff0 + k0);
      if(b1ok) rb1 = *(const float4*)(Bw + boff1 + k0);
    }
    bf16x8 af[4], bf[4];
    #pragma unroll
    for(int i=0;i<4;i++) af[i] = *(const bf16x8*)(As + (wm + i*16 + c)*40 + q*8);
    #pragma unroll
    for(int j=0;j<4;j++) bf[j] = *(const bf16x8*)(Bs + (wn + j*16 + c)*40 + q*8);
    #pragma unroll
    for(int i=0;i<4;i++)
      #pragma unroll
      for(int j=0;j<4;j++)
        acc[i][j] = __builtin_amdgcn_mfma_f32_16x16x32_bf16(af[i], bf[j], acc[i][j], 0, 0, 0);
    // single barrier per iter: ping-pong buffer makes the 2nd barrier redundant
  }
  __syncthreads();

  // epilogue: per-wave 16x64 transpose via LDS (stride 21, scalar writes: ~2-way)
  float* sw = (float*)Ssh + wave*(64*21);   // 5376 B per wave
  int lrow = lane >> 2, ln4 = lane & 3;
  #pragma unroll
  for(int i=0;i<4;i++){
    #pragma unroll
    for(int j=0;j<4;j++){
      int col = j*16 + c;
      #pragma unroll
      for(int r2=0;r2<4;r2++) sw[col*21 + q*4 + r2] = acc[i][j][r2];
    }
    int row_g = m0 + wm + i*16 + lrow;
    int s = sym_i[row_g];
    const unsigned int* bt = tokbits + (size_t)s*TOKB_STRIDE;
    float* orow = out + OFF_EXACT + (size_t)row_g*VT;
    #pragma unroll
    for(int s4=0;s4<4;s4++){
      int colo = ln4*4 + s4*16;
      int n = n0 + wn + colo;
      if(n < VT){
        float4 bt4 = *(const float4*)&sBtok[wn + colo];
        unsigned int wb = bt[n >> 5];
        int sh = n & 31;
        float4 o;
        o.x = sw[(colo+0)*21 + lrow] + bt4.x + (((wb>>(sh+0))&1u) ? 0.f : LOG_TINY);
        o.y = sw[(colo+1)*21 + lrow] + bt4.y + (((wb>>(sh+1))&1u) ? 0.f : LOG_TINY);
        o.z = sw[(colo+2)*21 + lrow] + bt4.z + (((wb>>(sh+2))&1u) ? 0.f : LOG_TINY);
        o.w = sw[(colo+3)*21 + lrow] + bt4.w + (((wb>>(sh+3))&1u) ? 0.f : LOG_TINY);
        *(float4*)(orow + n) = o;
      }
    }
  }
}

extern "C" void kernel_launch(void* const* d_in, const int* in_sizes, int n_in,
                              void* d_out, int out_size, void* d_ws, size_t ws_size,
                              hipStream_t stream) {
  const int*   lhs       = (const int*)  d_in[0];
  const int*   lhs_mask  = (const int*)  d_in[1];
  const float* tree_state= (const float*)d_in[2];
  const int*   gg        = (const int*)  d_in[3];
  const float* emb       = (const float*)d_in[4];
  const float* mem       = (const float*)d_in[5];
  const float* Wx        = (const float*)d_in[6];
  const float* Wh        = (const float*)d_in[7];
  const float* bx        = (const float*)d_in[8];
  const float* bh        = (const float*)d_in[9];
  const float* Wc        = (const float*)d_in[10];
  const float* bc        = (const float*)d_in[11];
  const float* Wsym      = (const float*)d_in[12];
  const float* bsym      = (const float*)d_in[13];
  const float* Wtok      = (const float*)d_in[14];
  const float* btok      = (const float*)d_in[15];
  const float* tok_table = (const float*)d_in[16];
  float* out = (float*)d_out;

  float* W    = (float*)d_ws;
  float* gh   = W;                        // 196608 floats
  float* ts   = gh  + BB*D3;              // 65536
  float* soa  = ts  + BB*DD;              // 65536
  float* cl   = soa + BB*DD;              // 5,120,000
  float* EW   = cl  + (size_t)SEQN*BB*VV; // 1,536,000
  int*   sym_i= (int*)(EW + VV*D3);       // 2560
  unsigned short* Abf  = (unsigned short*)(sym_i + BB*SEQN);  // 2560*512 ushorts
  unsigned short* WtokB= Abf + (size_t)BB*SEQN*D2;            // 10000*512 ushorts
  unsigned int* tokbits= (unsigned int*)(WtokB + (size_t)VT*D2); // 2000*320 uints

  hipMemcpyAsync(ts, tree_state, BB*DD*sizeof(float), hipMemcpyDeviceToDevice, stream);

  k_pass<<<(2*BB + BB*OPTN*4*SEQN + 255)/256, 256, 0, stream>>>(lhs, lhs_mask, gg, out);
  k_tokbits<<<2048, 256, 0, stream>>>(tok_table, tokbits);
  k_wtokT<<<dim3((VT+63)/64, D2/32), 256, 0, stream>>>(Wtok, WtokB);
  k_gh<<<dim3(BB,3), 256, 0, stream>>>(tree_state, Wh, bh, gh);
  k_ew<<<dim3(D3/64, (VV+63)/64), 256, 0, stream>>>(emb, Wx, EW);

  for(int t=0; t<SEQN; t++){
    const float* cl_prev = (t == 0) ? nullptr : (cl + (size_t)(t-1)*BB*VV);
    k_step<<<BB, 256, 0, stream>>>(cl_prev, lhs, EW, gh, bx, tree_state, mem, Wc, bc, soa, ts);
    k_clogits<<<dim3(32,8), 256, 0, stream>>>(soa, Wsym, bsym, gg, t, cl);
  }

  k_opts<<<BB, 256, 0, stream>>>(cl, gg, emb, ts, out, sym_i, Abf);
  k_tok_mfma<<<NWG_TOK, 256, 0, stream>>>(Abf, WtokB, btok, tokbits, sym_i, out);
}

// Round 4
// 789.515 us; speedup vs baseline: 1.3967x; 1.0054x over previous
//
#include <hip/hip_runtime.h>
#include <math.h>

#define BB 256
#define DD 256
#define VV 2000
#define VT 10000
#define OPTN 16
#define SEQN 10
#define SRCN 40
#define D3 768
#define D2 512

#define LOG_TINY (-29.9336062f)

// output offsets (floats)
#define OFF_OPTS  (2*BB + BB*OPTN*4*SEQN)          // 164352
#define OFF_TOPO  (OFF_OPTS + BB*OPTN)             // 168448
#define OFF_EXACT (OFF_TOPO + 4*BB*SEQN)           // 178688

// tok bitmask: 2000 rows x 320 dwords (10240 bits >= 10000)
#define TOKB_STRIDE 320
#define TOKB_W 313   // used dwords per row (ceil(10000/32))

#define NWG_TOK 1580  // 79 n-blocks * 20 m-blocks

typedef __bf16 bf16x8 __attribute__((ext_vector_type(8)));
typedef float  f32x4  __attribute__((ext_vector_type(4)));

__device__ __forceinline__ float sigm(float x){ return 1.0f/(1.0f+expf(-x)); }
__device__ __forceinline__ unsigned short f2bf(float x){
  union { float f; unsigned int u; } v; v.f = x;
  unsigned int r = (v.u + 0x7FFF + ((v.u >> 16) & 1)) >> 16;
  return (unsigned short)r;
}

// gh = tree_state @ Wh + bh  (constant across steps: gru uses outer tree_state)
__global__ void k_gh(const float* __restrict__ ts0, const float* __restrict__ Wh,
                     const float* __restrict__ bh, float* __restrict__ gh){
  int b = blockIdx.x;
  int j = blockIdx.y*256 + threadIdx.x;
  __shared__ float hsh[DD];
  hsh[threadIdx.x] = ts0[b*DD + threadIdx.x];
  __syncthreads();
  float a0 = bh[j], a1 = 0.f, a2 = 0.f, a3 = 0.f;
  #pragma unroll 4
  for(int k=0;k<DD;k+=4){
    a0 = fmaf(hsh[k+0], Wh[(k+0)*D3 + j], a0);
    a1 = fmaf(hsh[k+1], Wh[(k+1)*D3 + j], a1);
    a2 = fmaf(hsh[k+2], Wh[(k+2)*D3 + j], a2);
    a3 = fmaf(hsh[k+3], Wh[(k+3)*D3 + j], a3);
  }
  gh[b*D3 + j] = (a0+a1)+(a2+a3);
}

// EW = emb @ Wx  (2000 x 768, K=256) fp32 64x64 tiler
__global__ void k_ew(const float* __restrict__ emb, const float* __restrict__ Wx,
                     float* __restrict__ EW){
  __shared__ float As[16][64];
  __shared__ float Bs[16][64];
  int tid = threadIdx.x;
  int tx = tid & 15, ty = tid >> 4;
  int m0 = blockIdx.y*64, n0 = blockIdx.x*64;
  float acc[4][4];
  #pragma unroll
  for(int i=0;i<4;i++){ acc[i][0]=0.f; acc[i][1]=0.f; acc[i][2]=0.f; acc[i][3]=0.f; }
  for(int k0=0;k0<DD;k0+=16){
    {
      int row = tid >> 2, kk = (tid & 3)*4;
      int m = m0 + row;
      float4 av = {0,0,0,0};
      if(m < VV) av = *(const float4*)&emb[m*DD + k0 + kk];
      As[kk+0][row]=av.x; As[kk+1][row]=av.y; As[kk+2][row]=av.z; As[kk+3][row]=av.w;
    }
    {
      int r = tid >> 4, c2 = (tid & 15)*4;
      float4 bv = *(const float4*)&Wx[(k0+r)*D3 + n0 + c2];
      *(float4*)&Bs[r][c2] = bv;
    }
    __syncthreads();
    #pragma unroll
    for(int k=0;k<16;k++){
      float4 a4 = *(const float4*)&As[k][ty*4];
      float4 b4 = *(const float4*)&Bs[k][tx*4];
      float av[4] = {a4.x,a4.y,a4.z,a4.w};
      float bw[4] = {b4.x,b4.y,b4.z,b4.w};
      #pragma unroll
      for(int i=0;i<4;i++)
        #pragma unroll
        for(int j=0;j<4;j++) acc[i][j] = fmaf(av[i], bw[j], acc[i][j]);
    }
    __syncthreads();
  }
  #pragma unroll
  for(int i=0;i<4;i++){
    int m = m0 + ty*4 + i;
    if(m < VV){
      #pragma unroll
      for(int j=0;j<4;j++) EW[m*D3 + n0 + tx*4 + j] = acc[i][j];
    }
  }
}

// Wtok [512][10000] fp32 -> WtokB [10000][512] bf16 (transpose + convert)
__global__ void k_wtokT(const float* __restrict__ Wtok, unsigned short* __restrict__ WtokB){
  __shared__ float tile[32][65];
  int tid = threadIdx.x;
  int n0 = blockIdx.x*64, k0 = blockIdx.y*32;
  #pragma unroll
  for(int p=0;p<8;p++){
    int idx = tid + p*256;
    int kk = idx >> 6, nn = idx & 63;
    int n = n0 + nn;
    tile[kk][nn] = (n < VT) ? Wtok[(size_t)(k0+kk)*VT + n] : 0.f;
  }
  __syncthreads();
  #pragma unroll
  for(int p=0;p<4;p++){
    int idx = tid + p*256;
    int nn = idx >> 4, kk = (idx & 15)*2;
    int n = n0 + nn;
    if(n < VT){
      ushort2 v;
      v.x = f2bf(tile[kk][nn]);
      v.y = f2bf(tile[kk+1][nn]);
      *(ushort2*)&WtokB[(size_t)n*D2 + k0 + kk] = v;
    }
  }
}

// tok_table (binary 0/1) -> bitmask, 1 bit per entry. log(tt+1e-13) is EXACTLY
// (tt ? 0 : LOG_TINY) in fp32. Grid-stride, float4 loads, 1 dword out/thread.
__global__ __launch_bounds__(256) void k_tokbits(const float* __restrict__ tok_table,
                                                 unsigned int* __restrict__ bits){
  int idx = blockIdx.x*256 + threadIdx.x;
  const int total = VV*TOKB_W;
  for(; idx < total; idx += gridDim.x*256){
    int v = idx / TOKB_W, w = idx - v*TOKB_W;
    const float* row = tok_table + (size_t)v*VT + w*32;
    unsigned int bv = 0;
    if(w*32 + 32 <= VT){
      #pragma unroll
      for(int k=0;k<8;k++){
        float4 x = *(const float4*)(row + k*4);
        bv |= (x.x>0.5f?1u:0u) << (k*4+0);
        bv |= (x.y>0.5f?1u:0u) << (k*4+1);
        bv |= (x.z>0.5f?1u:0u) << (k*4+2);
        bv |= (x.w>0.5f?1u:0u) << (k*4+3);
      }
    } else {
      for(int k=0;k<32;k++){
        int n = w*32 + k;
        if(n < VT && row[k] > 0.5f) bv |= 1u << k;
      }
    }
    bits[v*TOKB_STRIDE + w] = bv;
  }
}

// fused per-step: sym from precomputed argmax key; gates from EW gather; gru;
// attention; soa=tanh([ctx,h]@Wc+bc); ts update
__global__ void k_step(const unsigned long long* __restrict__ key_row,
                       const int* __restrict__ lhs,
                       const float* __restrict__ EW, const float* __restrict__ gh,
                       const float* __restrict__ bx, const float* __restrict__ ts0,
                       const float* __restrict__ mem, const float* __restrict__ Wc,
                       const float* __restrict__ bc, float* __restrict__ soa,
                       float* __restrict__ ts){
  int b = blockIdx.x, tid = threadIdx.x;
  int lane = tid & 63, wv = tid >> 6;
  __shared__ float hs[DD], cs[DD], sc[SRCN];
  int sym;
  if(key_row){
    // argmax was folded into k_clogits: key = (enc(val)<<32) | (0x7FFFFFFF - n)
    sym = 0x7FFFFFFF - (int)(unsigned int)(key_row[b] & 0xFFFFFFFFull);
  } else {
    sym = lhs[b];
  }
  const float* ew = EW + sym*D3;
  const float* ghb = gh + b*D3;
  float r = sigm(ew[tid]     + bx[tid]     + ghb[tid]);
  float z = sigm(ew[256+tid] + bx[256+tid] + ghb[256+tid]);
  float n = tanhf(ew[512+tid] + bx[512+tid] + r*ghb[512+tid]);
  float h = (1.0f - z)*n + z*ts0[b*DD + tid];
  hs[tid] = h;
  __syncthreads();
  for(int s = wv; s < SRCN; s += 4){
    float p = 0.f;
    const float* mrow = mem + (size_t)(b*SRCN + s)*DD;
    #pragma unroll 4
    for(int d = lane; d < DD; d += 64) p = fmaf(hs[d], mrow[d], p);
    for(int off=32; off; off>>=1) p += __shfl_down(p, off, 64);
    if(lane==0) sc[s] = p;
  }
  __syncthreads();
  // wave-parallel softmax over the 40 scores (first wave only)
  if(tid < 64){
    float v = (tid < SRCN) ? sc[tid] : -1e30f;
    float mx = v;
    for(int off=32; off; off>>=1) mx = fmaxf(mx, __shfl_xor(mx, off, 64));
    float e = (tid < SRCN) ? expf(v - mx) : 0.f;
    float sum = e;
    for(int off=32; off; off>>=1) sum += __shfl_xor(sum, off, 64);
    if(tid < SRCN) sc[tid] = e / sum;
  }
  __syncthreads();
  float c = 0.f;
  #pragma unroll 8
  for(int s=0;s<SRCN;s++) c = fmaf(sc[s], mem[(size_t)(b*SRCN+s)*DD + tid], c);
  cs[tid] = c;
  __syncthreads();
  // [ctx|h] @ Wc — 8 independent accumulators (latency-exposed at 1 block/CU)
  float a0 = bc[tid], a1=0.f, a2=0.f, a3=0.f, a4=0.f, a5=0.f, a6=0.f, a7=0.f;
  #pragma unroll 4
  for(int k=0;k<DD;k+=8){
    a0 = fmaf(cs[k+0], Wc[(k+0)*DD + tid], a0);
    a1 = fmaf(cs[k+1], Wc[(k+1)*DD + tid], a1);
    a2 = fmaf(cs[k+2], Wc[(k+2)*DD + tid], a2);
    a3 = fmaf(cs[k+3], Wc[(k+3)*DD + tid], a3);
    a4 = fmaf(cs[k+4], Wc[(k+4)*DD + tid], a4);
    a5 = fmaf(cs[k+5], Wc[(k+5)*DD + tid], a5);
    a6 = fmaf(cs[k+6], Wc[(k+6)*DD + tid], a6);
    a7 = fmaf(cs[k+7], Wc[(k+7)*DD + tid], a7);
  }
  #pragma unroll 4
  for(int k=0;k<DD;k+=8){
    a0 = fmaf(hs[k+0], Wc[(k+0+DD)*DD + tid], a0);
    a1 = fmaf(hs[k+1], Wc[(k+1+DD)*DD + tid], a1);
    a2 = fmaf(hs[k+2], Wc[(k+2+DD)*DD + tid], a2);
    a3 = fmaf(hs[k+3], Wc[(k+3+DD)*DD + tid], a3);
    a4 = fmaf(hs[k+4], Wc[(k+4+DD)*DD + tid], a4);
    a5 = fmaf(hs[k+5], Wc[(k+5+DD)*DD + tid], a5);
    a6 = fmaf(hs[k+6], Wc[(k+6+DD)*DD + tid], a6);
    a7 = fmaf(hs[k+7], Wc[(k+7+DD)*DD + tid], a7);
  }
  float sv = tanhf(((a0+a1)+(a2+a3)) + ((a4+a5)+(a6+a7)));
  soa[b*DD + tid] = sv;
  ts[b*DD + tid] = tanhf(ts[b*DD + tid] + sv);
}

// clogits[t][b][v] = soa[b]@Wsym[:,v] + bsym[v] + (allowed? 0 : LOG_TINY)
// 32x64 tiles -> 256 blocks. allowed-mask via 64-bit LDS bitmask.
// Also folds per-row argmax (packed u64 atomicMax; exact argmax+smallest-index
// tie-break semantics) so the next k_step needs no 2000-scan.
__global__ void k_clogits(const float* __restrict__ A, const float* __restrict__ Wsym,
                          const float* __restrict__ bsym, const int* __restrict__ gg,
                          int t, float* __restrict__ cl,
                          unsigned long long* __restrict__ keys){
  __shared__ float As[16][32];
  __shared__ float Bs[16][64];
  __shared__ unsigned int selb[32][2];
  int tid = threadIdx.x;
  int tx = tid & 15, ty = tid >> 4;
  int m0 = blockIdx.y*32, n0 = blockIdx.x*64;
  if(tid < 64) selb[tid>>1][tid&1] = 0u;
  __syncthreads();
  for(int idx = tid; idx < 32*OPTN; idx += 256){
    int i = idx >> 4, o = idx & 15;
    int bb = m0 + i;
    int base = ((bb*OPTN + o)*4)*SEQN + t;
    int mk = gg[base + 3*SEQN];
    int v = mk ? gg[base] : -1;
    unsigned int d = (unsigned int)(v - n0);
    if(d < 64u) atomicOr(&selb[i][d>>5], 1u << (d&31));
  }
  float acc[2][4];
  #pragma unroll
  for(int i=0;i<2;i++){ acc[i][0]=0.f; acc[i][1]=0.f; acc[i][2]=0.f; acc[i][3]=0.f; }
  for(int k0=0;k0<DD;k0+=16){
    if(tid < 128){
      int row = tid >> 2, kk = (tid & 3)*4;
      float4 av = *(const float4*)&A[(m0+row)*DD + k0 + kk];
      As[kk+0][row]=av.x; As[kk+1][row]=av.y; As[kk+2][row]=av.z; As[kk+3][row]=av.w;
    }
    {
      int r = tid >> 4, c2 = (tid & 15)*4;
      int n = n0 + c2;
      float4 bv;
      if(n + 3 < VV){ bv = *(const float4*)&Wsym[(k0+r)*VV + n]; }
      else {
        bv.x = (n+0<VV)? Wsym[(k0+r)*VV + n+0] : 0.f;
        bv.y = (n+1<VV)? Wsym[(k0+r)*VV + n+1] : 0.f;
        bv.z = (n+2<VV)? Wsym[(k0+r)*VV + n+2] : 0.f;
        bv.w = (n+3<VV)? Wsym[(k0+r)*VV + n+3] : 0.f;
      }
      *(float4*)&Bs[r][c2] = bv;
    }
    __syncthreads();
    #pragma unroll
    for(int k=0;k<16;k++){
      float a0 = As[k][ty*2+0];
      float a1 = As[k][ty*2+1];
      float4 b4 = *(const float4*)&Bs[k][tx*4];
      acc[0][0] = fmaf(a0, b4.x, acc[0][0]);
      acc[0][1] = fmaf(a0, b4.y, acc[0][1]);
      acc[0][2] = fmaf(a0, b4.z, acc[0][2]);
      acc[0][3] = fmaf(a0, b4.w, acc[0][3]);
      acc[1][0] = fmaf(a1, b4.x, acc[1][0]);
      acc[1][1] = fmaf(a1, b4.y, acc[1][1]);
      acc[1][2] = fmaf(a1, b4.z, acc[1][2]);
      acc[1][3] = fmaf(a1, b4.w, acc[1][3]);
    }
    __syncthreads();
  }
  #pragma unroll
  for(int i=0;i<2;i++){
    int m = m0 + ty*2 + i;
    unsigned int s0 = selb[ty*2+i][0], s1 = selb[ty*2+i][1];
    float vals[4];
    #pragma unroll
    for(int j=0;j<4;j++){
      int n = n0 + tx*4 + j;
      int nn = tx*4 + j;
      unsigned int wb = (nn < 32) ? s0 : s1;
      vals[j] = acc[i][j] + ((n < VV) ? bsym[n] : 0.f) + (((wb >> (nn&31)) & 1u) ? 0.f : LOG_TINY);
    }
    int nb = n0 + tx*4;
    if(nb + 3 < VV){
      float4 o; o.x=vals[0]; o.y=vals[1]; o.z=vals[2]; o.w=vals[3];
      *(float4*)&cl[((size_t)t*BB + m)*VV + nb] = o;
    } else {
      #pragma unroll
      for(int j=0;j<4;j++){
        int n = nb + j;
        if(n < VV) cl[((size_t)t*BB + m)*VV + n] = vals[j];
      }
    }
    // local argmax over this thread's 4 cols (ascending n => smallest-index tie)
    float bv = -3.0e30f; int bn = 0x7FFFFFF;
    #pragma unroll
    for(int j=0;j<4;j++){
      int n = nb + j;
      if(n < VV && vals[j] > bv){ bv = vals[j]; bn = n; }
    }
    // reduce across the 16 tx-lanes (same ty => same 16-lane subgroup)
    #pragma unroll
    for(int o=1;o<16;o<<=1){
      float ov = __shfl_xor(bv, o, 64);
      int   on = __shfl_xor(bn, o, 64);
      if(ov > bv || (ov == bv && on < bn)){ bv = ov; bn = on; }
    }
    if(tx == 0){
      unsigned int e = __float_as_uint(bv);
      e = (e & 0x80000000u) ? ~e : (e | 0x80000000u);
      unsigned long long key = ((unsigned long long)e << 32) | (unsigned int)(0x7FFFFFFF - bn);
      atomicMax(&keys[m], key);
    }
  }
}

// per-b: lse for all t; opts_logp; best; topo outputs; sym_i; build bf16 A rows
__global__ void k_opts(const float* __restrict__ cl, const int* __restrict__ gg,
                       const float* __restrict__ emb, const float* __restrict__ ts,
                       float* __restrict__ out, int* __restrict__ sym_i,
                       unsigned short* __restrict__ A){
  int b = blockIdx.x, tid = threadIdx.x;
  int lane = tid & 63, wv = tid >> 6;
  __shared__ float redm[4], reds[4];
  __shared__ float lse_sh[SEQN];
  __shared__ float sacc[OPTN];
  __shared__ int ssym[SEQN];
  __shared__ int sbest;
  for(int t=0;t<SEQN;t++){
    const float* row = cl + ((size_t)t*BB + b)*VV;
    float mx = -1e30f;
    for(int v=tid; v<VV; v+=256) mx = fmaxf(mx, row[v]);
    for(int off=32; off; off>>=1) mx = fmaxf(mx, __shfl_xor(mx, off, 64));
    if(lane==0) redm[wv] = mx;
    __syncthreads();
    float gmx = fmaxf(fmaxf(redm[0],redm[1]), fmaxf(redm[2],redm[3]));
    float sum = 0.f;
    for(int v=tid; v<VV; v+=256) sum += expf(row[v]-gmx);
    for(int off=32; off; off>>=1) sum += __shfl_xor(sum, off, 64);
    if(lane==0) reds[wv] = sum;
    __syncthreads();
    if(tid==0) lse_sh[t] = gmx + logf(reds[0]+reds[1]+reds[2]+reds[3]);
    __syncthreads();
  }
  if(tid < OPTN){
    int o = tid;
    float acc = 0.f;
    for(int t=0;t<SEQN;t++){
      int base = ((b*OPTN + o)*4)*SEQN + t;
      int mk = gg[base + 3*SEQN];
      if(mk){
        int v = gg[base];
        float p = expf(cl[((size_t)t*BB + b)*VV + v] - lse_sh[t]);
        acc += logf(p + 1e-13f);
      }
    }
    sacc[o] = acc;
    out[OFF_OPTS + b*OPTN + o] = acc;
  }
  __syncthreads();
  if(tid==0){
    float mx = sacc[0]; int mi = 0;
    for(int o=1;o<OPTN;o++) if(sacc[o] > mx){ mx = sacc[o]; mi = o; }
    sbest = mi;
  }
  __syncthreads();
  if(tid < 4*SEQN){
    int c = tid/SEQN, t = tid%SEQN;
    int val = gg[((b*OPTN + sbest)*4 + c)*SEQN + t];
    out[OFF_TOPO + c*(BB*SEQN) + b*SEQN + t] = (float)val;
    if(c==0){ sym_i[b*SEQN + t] = val; ssym[t] = val; }
  }
  __syncthreads();
  // build A rows m=b*10+t : [emb[sym] | ts[b]] as bf16
  for(int idx = tid; idx < SEQN*D2; idx += 256){
    int t = idx >> 9, k = idx & 511;
    float val = (k < DD) ? emb[ssym[t]*DD + k] : ts[b*DD + (k-DD)];
    A[(size_t)(b*SEQN + t)*D2 + k] = f2bf(val);
  }
}

// passthrough outputs 0..2 as float
__global__ void k_pass(const int* __restrict__ lhs, const int* __restrict__ lhs_mask,
                       const int* __restrict__ gg, float* __restrict__ out){
  int i = blockIdx.x*256 + threadIdx.x;
  if(i < BB) out[i] = (float)lhs[i];
  else if(i < 2*BB) out[i] = (float)lhs_mask[i - BB];
  else if(i < 2*BB + BB*OPTN*4*SEQN) out[2*BB + (i - 2*BB)] = (float)gg[i - 2*BB];
}

// exact_logit: bf16 MFMA GEMM, M=2560 x N=10000, K=512, 128x128 tiles.
// v4: A fragments direct from global (L1/L2-resident, no LDS), B-only ping-pong
// LDS (20KB), 1-iter-ahead register prefetch for both A and B, one barrier/iter.
// Epilogue transpose reuses the B buffers (stride 17). MFMA order bit-identical.
__global__ __launch_bounds__(256) void k_tok_mfma(
    const unsigned short* __restrict__ A, const unsigned short* __restrict__ Bw,
    const float* __restrict__ btok, const unsigned int* __restrict__ tokbits,
    const int* __restrict__ sym_i, float* __restrict__ out){
  __shared__ __align__(16) unsigned short Bsh[2*5120];  // 20 KB (also epilogue staging)
  __shared__ float sBtok[128];
  int tid = threadIdx.x;
  int lane = tid & 63, wave = tid >> 6;
  int c = lane & 15, q = lane >> 4;
  int wm = (wave >> 1)*64, wn = (wave & 1)*64;

  // bijective XCD swizzle (8 XCDs), n-major ordering for B-panel L2 locality
  int id = blockIdx.x;
  int xcd = id & 7, off = id >> 3;
  const int qq = NWG_TOK >> 3, rr = NWG_TOK & 7;  // 197, 4
  int start = (xcd < rr) ? xcd*(qq+1) : rr*(qq+1) + (xcd-rr)*qq;
  int ord = start + off;
  int mb = ord % 20, nb = ord / 20;
  int m0 = mb*128, n0 = nb*128;

  if(tid < 128){
    int n = n0 + tid;
    sBtok[tid] = (n < VT) ? btok[n] : 0.f;
  }
  f32x4 acc[4][4];
  #pragma unroll
  for(int i=0;i<4;i++)
    #pragma unroll
    for(int j=0;j<4;j++) acc[i][j] = (f32x4){0.f,0.f,0.f,0.f};

  // B staging mapping: thread -> rows (brow, brow+64), 16B chunk bch
  int brow = tid >> 2;
  int bch  = (tid & 3)*8;
  int bnr0 = n0 + brow, bnr1 = n0 + 64 + brow;
  bool ok0 = bnr0 < VT, ok1 = bnr1 < VT;
  const unsigned short* bp0 = Bw + (size_t)bnr0*D2 + bch;
  const unsigned short* bp1 = Bw + (size_t)bnr1*D2 + bch;
  const float4 fz = {0.f,0.f,0.f,0.f};

  // A fragment row pointers (per-lane direct global loads; k advances via imm offset)
  const unsigned short* ap0 = A + (size_t)(m0 + wm +  0 + c)*D2 + q*8;
  const unsigned short* ap1 = A + (size_t)(m0 + wm + 16 + c)*D2 + q*8;
  const unsigned short* ap2 = A + (size_t)(m0 + wm + 32 + c)*D2 + q*8;
  const unsigned short* ap3 = A + (size_t)(m0 + wm + 48 + c)*D2 + q*8;

  // prologue: B tile0 -> buf0; issue B tile1 + A tile0 prefetch
  float4 r0 = ok0 ? *(const float4*)(bp0) : fz;
  float4 r1 = ok1 ? *(const float4*)(bp1) : fz;
  *(float4*)(Bsh + brow*40 + bch)      = r0;
  *(float4*)(Bsh + (64+brow)*40 + bch) = r1;
  r0 = ok0 ? *(const float4*)(bp0 + 32) : fz;
  r1 = ok1 ? *(const float4*)(bp1 + 32) : fz;
  bf16x8 afp[4];
  afp[0] = *(const bf16x8*)(ap0);
  afp[1] = *(const bf16x8*)(ap1);
  afp[2] = *(const bf16x8*)(ap2);
  afp[3] = *(const bf16x8*)(ap3);
  __syncthreads();

  #pragma unroll
  for(int t=0; t<16; t++){
    unsigned short* Bcur = Bsh + (t&1)*5120;
    unsigned short* Bnxt = Bsh + ((t+1)&1)*5120;
    if(t < 15){
      // write tile t+1 (regs loaded one iter ago; overwrites tile t-1, whose
      // reads completed before the previous barrier)
      *(float4*)(Bnxt + brow*40 + bch)      = r0;
      *(float4*)(Bnxt + (64+brow)*40 + bch) = r1;
      if(t < 14){
        r0 = ok0 ? *(const float4*)(bp0 + (t+2)*32) : fz;
        r1 = ok1 ? *(const float4*)(bp1 + (t+2)*32) : fz;
      }
    }
    bf16x8 af[4];
    #pragma unroll
    for(int i=0;i<4;i++) af[i] = afp[i];
    if(t < 15){
      afp[0] = *(const bf16x8*)(ap0 + (t+1)*32);
      afp[1] = *(const bf16x8*)(ap1 + (t+1)*32);
      afp[2] = *(const bf16x8*)(ap2 + (t+1)*32);
      afp[3] = *(const bf16x8*)(ap3 + (t+1)*32);
    }
    bf16x8 bf[4];
    #pragma unroll
    for(int j=0;j<4;j++) bf[j] = *(const bf16x8*)(Bcur + (wn + j*16 + c)*40 + q*8);
    #pragma unroll
    for(int i=0;i<4;i++)
      #pragma unroll
      for(int j=0;j<4;j++)
        acc[i][j] = __builtin_amdgcn_mfma_f32_16x16x32_bf16(af[i], bf[j], acc[i][j], 0, 0, 0);
    __syncthreads();
  }

  // epilogue: per-wave 16x64 transpose via LDS (stride 17, fits in Bsh: 4*4352B)
  float* sw = (float*)Bsh + wave*(64*17);
  int lrow = lane >> 2, ln4 = lane & 3;
  #pragma unroll
  for(int i=0;i<4;i++){
    #pragma unroll
    for(int j=0;j<4;j++){
      int col = j*16 + c;
      #pragma unroll
      for(int r2=0;r2<4;r2++) sw[col*17 + q*4 + r2] = acc[i][j][r2];
    }
    int row_g = m0 + wm + i*16 + lrow;
    int s = sym_i[row_g];
    const unsigned int* bt = tokbits + (size_t)s*TOKB_STRIDE;
    float* orow = out + OFF_EXACT + (size_t)row_g*VT;
    #pragma unroll
    for(int s4=0;s4<4;s4++){
      int colo = ln4*4 + s4*16;
      int n = n0 + wn + colo;
      if(n < VT){
        float4 bt4 = *(const float4*)&sBtok[wn + colo];
        unsigned int wb = bt[n >> 5];
        int sh = n & 31;
        float4 o;
        o.x = sw[(colo+0)*17 + lrow] + bt4.x + (((wb>>(sh+0))&1u) ? 0.f : LOG_TINY);
        o.y = sw[(colo+1)*17 + lrow] + bt4.y + (((wb>>(sh+1))&1u) ? 0.f : LOG_TINY);
        o.z = sw[(colo+2)*17 + lrow] + bt4.z + (((wb>>(sh+2))&1u) ? 0.f : LOG_TINY);
        o.w = sw[(colo+3)*17 + lrow] + bt4.w + (((wb>>(sh+3))&1u) ? 0.f : LOG_TINY);
        *(float4*)(orow + n) = o;
      }
    }
    __syncthreads();  // waves reuse disjoint regions, but keep i-steps in lockstep
                      // with LDS reads drained before next i overwrite (safe, cheap)
  }
}

extern "C" void kernel_launch(void* const* d_in, const int* in_sizes, int n_in,
                              void* d_out, int out_size, void* d_ws, size_t ws_size,
                              hipStream_t stream) {
  const int*   lhs       = (const int*)  d_in[0];
  const int*   lhs_mask  = (const int*)  d_in[1];
  const float* tree_state= (const float*)d_in[2];
  const int*   gg        = (const int*)  d_in[3];
  const float* emb       = (const float*)d_in[4];
  const float* mem       = (const float*)d_in[5];
  const float* Wx        = (const float*)d_in[6];
  const float* Wh        = (const float*)d_in[7];
  const float* bx        = (const float*)d_in[8];
  const float* bh        = (const float*)d_in[9];
  const float* Wc        = (const float*)d_in[10];
  const float* bc        = (const float*)d_in[11];
  const float* Wsym      = (const float*)d_in[12];
  const float* bsym      = (const float*)d_in[13];
  const float* Wtok      = (const float*)d_in[14];
  const float* btok      = (const float*)d_in[15];
  const float* tok_table = (const float*)d_in[16];
  float* out = (float*)d_out;

  // ws layout: keys first (8B-aligned), then float regions
  unsigned long long* keys = (unsigned long long*)d_ws;   // SEQN*BB u64 = 20480 B
  float* W    = (float*)d_ws + 2*SEQN*BB;  // 5120 floats offset
  float* gh   = W;                        // 196608 floats
  float* ts   = gh  + BB*D3;              // 65536
  float* soa  = ts  + BB*DD;              // 65536
  float* cl   = soa + BB*DD;              // 5,120,000
  float* EW   = cl  + (size_t)SEQN*BB*VV; // 1,536,000
  int*   sym_i= (int*)(EW + VV*D3);       // 2560
  unsigned short* Abf  = (unsigned short*)(sym_i + BB*SEQN);  // 2560*512 ushorts
  unsigned short* WtokB= Abf + (size_t)BB*SEQN*D2;            // 10000*512 ushorts
  unsigned int* tokbits= (unsigned int*)(WtokB + (size_t)VT*D2); // 2000*320 uints

  hipMemcpyAsync(ts, tree_state, BB*DD*sizeof(float), hipMemcpyDeviceToDevice, stream);
  hipMemsetAsync(keys, 0, SEQN*BB*sizeof(unsigned long long), stream);

  k_pass<<<(2*BB + BB*OPTN*4*SEQN + 255)/256, 256, 0, stream>>>(lhs, lhs_mask, gg, out);
  k_tokbits<<<2048, 256, 0, stream>>>(tok_table, tokbits);
  k_wtokT<<<dim3((VT+63)/64, D2/32), 256, 0, stream>>>(Wtok, WtokB);
  k_gh<<<dim3(BB,3), 256, 0, stream>>>(tree_state, Wh, bh, gh);
  k_ew<<<dim3(D3/64, (VV+63)/64), 256, 0, stream>>>(emb, Wx, EW);

  for(int t=0; t<SEQN; t++){
    const unsigned long long* key_row = (t == 0) ? nullptr : (keys + (size_t)(t-1)*BB);
    k_step<<<BB, 256, 0, stream>>>(key_row, lhs, EW, gh, bx, tree_state, mem, Wc, bc, soa, ts);
    k_clogits<<<dim3(32,8), 256, 0, stream>>>(soa, Wsym, bsym, gg, t, cl, keys + (size_t)t*BB);
  }

  k_opts<<<BB, 256, 0, stream>>>(cl, gg, emb, ts, out, sym_i, Abf);
  k_tok_mfma<<<NWG_TOK, 256, 0, stream>>>(Abf, WtokB, btok, tokbits, sym_i, out);
}